// Round 4
// baseline (1562.667 us; speedup 1.0000x reference)
//
#include <hip/hip_runtime.h>
#include <hip/hip_bf16.h>
#include <cstdint>

#define NN 50000
#define NE 800000
#define HD 128
#define OD 64
#define NG 64
#define POOL_ROWS 256
#define NBUCK 196          // ceil(50000/256) coarse buckets of 256 dst
#define SCHUNK 4096        // edges per hist/scatter block
#define SBLOCKS 196        // ceil(800000/4096)
#define NAGG 391           // ceil(50000/128) agg blocks of 128 dst

typedef unsigned int uint32;
typedef unsigned short u16;

// round-to-nearest-even f32 -> bf16 bits
static __device__ __forceinline__ u16 f2bf(float f) {
    uint32 u = __float_as_uint(f);
    u += 0x7fffu + ((u >> 16) & 1u);
    return (u16)(u >> 16);
}
static __device__ __forceinline__ float bf2f(u16 h) {
    return __uint_as_float(((uint32)h) << 16);
}

// ---------- fused degree count + coarse bucket histogram ----------

__global__ __launch_bounds__(256) void k_hist(const int* __restrict__ dst,
                                              int* __restrict__ cnt,
                                              int* __restrict__ bucket_cnt) {
    __shared__ int lh[256];
    int t = threadIdx.x;
    lh[t] = 0;
    __syncthreads();
    int e0 = blockIdx.x * SCHUNK;
    int ne = min(SCHUNK, NE - e0);
    for (int k = 0; k < 16; ++k) {
        int i = k * 256 + t;
        if (i < ne) {
            int d = dst[e0 + i];
            atomicAdd(&cnt[d], 1);
            atomicAdd(&lh[d >> 8], 1);
        }
    }
    __syncthreads();
    if (t < NBUCK && lh[t]) atomicAdd(&bucket_cnt[t], lh[t]);
}

__global__ void k_dinv(const int* __restrict__ cnt, float* __restrict__ dinv) {
    int v = blockIdx.x * 256 + threadIdx.x;
    if (v < NN) dinv[v] = rsqrtf((float)(cnt[v] + 1));  // +1 self-loop
}

// ---------- bucket exclusive scan (1 block) ----------

__global__ __launch_bounds__(256) void k_bscan(const int* __restrict__ bucket_cnt,
                                               int* __restrict__ bucket_base,
                                               int* __restrict__ bucket_fill) {
    __shared__ int s[256];
    int t = threadIdx.x;
    int v = (t < NBUCK) ? bucket_cnt[t] : 0;
    s[t] = v; __syncthreads();
    for (int off = 1; off < 256; off <<= 1) {
        int u = (t >= off) ? s[t - off] : 0;
        __syncthreads();
        s[t] += u;
        __syncthreads();
    }
    int excl = s[t] - v;
    if (t < NBUCK) { bucket_base[t] = excl; bucket_fill[t] = excl; }
    if (t == NBUCK - 1) bucket_base[NBUCK] = s[t];
}

// ---------- bucketed scatter of packed edge records, coalesced via LDS reorder ----------

__global__ __launch_bounds__(256) void k_scatter(const int* __restrict__ src,
                                                 const int* __restrict__ dst,
                                                 int* __restrict__ bucket_fill,
                                                 uint32* __restrict__ grec) {
    __shared__ uint32 rin[SCHUNK];
    __shared__ uint32 rout[SCHUNK];
    __shared__ int lh[256], ls[256], lf[256], lgb[256];
    int t = threadIdx.x;
    lh[t] = 0; lf[t] = 0;
    __syncthreads();
    int e0 = blockIdx.x * SCHUNK;
    int ne = min(SCHUNK, NE - e0);
    for (int k = 0; k < 16; ++k) {
        int i = k * 256 + t;
        if (i < ne) {
            uint32 rec = ((uint32)dst[e0 + i] << 16) | (uint32)src[e0 + i];
            rin[i] = rec;
            atomicAdd(&lh[rec >> 24], 1);
        }
    }
    __syncthreads();
    int v = lh[t];
    ls[t] = v; __syncthreads();
    for (int off = 1; off < 256; off <<= 1) {
        int u = (t >= off) ? ls[t - off] : 0;
        __syncthreads();
        ls[t] += u;
        __syncthreads();
    }
    int excl = ls[t] - v;
    __syncthreads();
    ls[t] = excl;
    if (t < NBUCK && v > 0) lgb[t] = atomicAdd(&bucket_fill[t], v);
    __syncthreads();
    for (int k = 0; k < 16; ++k) {
        int i = k * 256 + t;
        if (i < ne) {
            uint32 rec = rin[i];
            int b = rec >> 24;
            int p = ls[b] + atomicAdd(&lf[b], 1);
            rout[p] = rec;
        }
    }
    __syncthreads();
    for (int k = 0; k < 16; ++k) {
        int i = k * 256 + t;
        if (i < ne) {
            uint32 rec = rout[i];
            int b = rec >> 24;
            grec[lgb[b] + (i - ls[b])] = rec;
        }
    }
}

// ---------- GEMM: hp[r] = bf16( (X[r] @ W) * dinv[r] ),  X [nrows][128] fp32 ----------

__global__ __launch_bounds__(256, 2) void k_gemm(const float* __restrict__ X,
                                                 const float* __restrict__ W,
                                                 const float* __restrict__ dinv,
                                                 u16* __restrict__ out, int nrows) {
    __shared__ float wl[128 * 128];   // 64 KB
    __shared__ float xl[32 * 128];    // 16 KB
    {
        float4* wl4 = (float4*)wl;
        const float4* W4 = (const float4*)W;
        for (int i = threadIdx.x; i < 128 * 32; i += 256) wl4[i] = W4[i];
    }
    const int rg = threadIdx.x >> 5;
    const int cg = threadIdx.x & 31;
    const int ntiles = (nrows + 31) >> 5;
    for (int tile = blockIdx.x; tile < ntiles; tile += gridDim.x) {
        const int row0 = tile << 5;
        __syncthreads();
        for (int i = threadIdx.x; i < 32 * 32; i += 256) {
            int rr = row0 + (i >> 5);
            ((float4*)xl)[i] = (rr < nrows) ? ((const float4*)X)[rr * 32 + (i & 31)]
                                            : make_float4(0.f, 0.f, 0.f, 0.f);
        }
        __syncthreads();
        float acc[4][4];
#pragma unroll
        for (int a = 0; a < 4; ++a)
#pragma unroll
            for (int b = 0; b < 4; ++b) acc[a][b] = 0.f;
        const float4* wl4 = (const float4*)wl;
        const float4* xl4 = (const float4*)xl;
#pragma unroll 4
        for (int kq = 0; kq < 32; ++kq) {
            float4 w0 = wl4[(4 * kq + 0) * 32 + cg];
            float4 w1 = wl4[(4 * kq + 1) * 32 + cg];
            float4 w2 = wl4[(4 * kq + 2) * 32 + cg];
            float4 w3 = wl4[(4 * kq + 3) * 32 + cg];
#pragma unroll
            for (int r = 0; r < 4; ++r) {
                float4 xv = xl4[(rg * 4 + r) * 32 + kq];
                acc[r][0] += xv.x * w0.x + xv.y * w1.x + xv.z * w2.x + xv.w * w3.x;
                acc[r][1] += xv.x * w0.y + xv.y * w1.y + xv.z * w2.y + xv.w * w3.y;
                acc[r][2] += xv.x * w0.z + xv.y * w1.z + xv.z * w2.z + xv.w * w3.z;
                acc[r][3] += xv.x * w0.w + xv.y * w1.w + xv.z * w2.w + xv.w * w3.w;
            }
        }
#pragma unroll
        for (int r = 0; r < 4; ++r) {
            int rr = row0 + rg * 4 + r;
            if (rr < nrows) {
                float dv = dinv[rr];
                ushort4 o;
                o.x = f2bf(acc[r][0] * dv);
                o.y = f2bf(acc[r][1] * dv);
                o.z = f2bf(acc[r][2] * dv);
                o.w = f2bf(acc[r][3] * dv);
                ((ushort4*)out)[(size_t)rr * 32 + cg] = o;
            }
        }
    }
}

// ---------- bucketed aggregation: LDS fp32 accumulator for 128 dst rows ----------

__global__ __launch_bounds__(512, 2) void k_agg_b(const uint32* __restrict__ grec,
                                                  const int* __restrict__ bucket_base,
                                                  const u16* __restrict__ hps,
                                                  const float* __restrict__ dinv,
                                                  const float* __restrict__ bias,
                                                  float* __restrict__ out) {
    __shared__ float acc[128 * 128];   // 64 KB
    __shared__ float bias_l[128];
    const int t = threadIdx.x, lane = t & 63, wid = t >> 6;   // 8 waves
    const int v0 = blockIdx.x << 7;          // 128 dst rows per block
    const int pb = blockIdx.x >> 1;          // parent 256-dst bucket
    float4 z = make_float4(0.f, 0.f, 0.f, 0.f);
    for (int i = t; i < 4096; i += 512) ((float4*)acc)[i] = z;
    if (t < 128) bias_l[t] = bias[t];
    __syncthreads();
    const int rs = bucket_base[pb], re = bucket_base[pb + 1];
    for (int e0 = rs + wid * 8; e0 < re; e0 += 64) {
        int n = min(8, re - e0);
#pragma unroll
        for (int i = 0; i < 8; ++i) {
            if (i < n) {
                uint32 rec = grec[e0 + i];
                int dl = (int)(rec >> 16) - v0;
                if ((unsigned)dl < 128u) {
                    int s = (int)(rec & 0xffffu);
                    u16 a = hps[(size_t)s * 128 + lane];
                    u16 b = hps[(size_t)s * 128 + 64 + lane];
                    atomicAdd(&acc[dl * 128 + lane], bf2f(a));
                    atomicAdd(&acc[dl * 128 + 64 + lane], bf2f(b));
                }
            }
        }
    }
    __syncthreads();
    for (int r = wid; r < 128; r += 8) {
        int vtx = v0 + r;
        if (vtx >= NN) break;
        float sa = acc[r * 128 + lane] + bf2f(hps[(size_t)vtx * 128 + lane]);
        float sb = acc[r * 128 + 64 + lane] + bf2f(hps[(size_t)vtx * 128 + 64 + lane]);
        float dv = dinv[vtx];
        out[(size_t)vtx * 128 + lane] = fmaxf(sa * dv + bias_l[lane], 0.f);
        out[(size_t)vtx * 128 + 64 + lane] = fmaxf(sb * dv + bias_l[64 + lane], 0.f);
    }
}

// ---------- pooling stage 1: node-parallel segment-sum into pooled[64][128] ----------

__global__ __launch_bounds__(256) void k_pool1(const float* __restrict__ h,
                                               const int* __restrict__ batch,
                                               float* __restrict__ pooled) {
    __shared__ int bl[POOL_ROWS];
    const int row0 = blockIdx.x * POOL_ROWS;
    const int rend = min(row0 + POOL_ROWS, NN);
    const int nrows = rend - row0;
    for (int i = threadIdx.x; i < nrows; i += 256) bl[i] = batch[row0 + i];
    __syncthreads();
    const int col2 = threadIdx.x & 63;
    const int rp   = threadIdx.x >> 6;
    const float2* h2 = (const float2*)h;
    float2 acc = make_float2(0.f, 0.f);
    int curg = -1;
    for (int i = rp; i < nrows; i += 4) {
        int g = bl[i];
        if (g != curg) {
            if (curg >= 0) {
                atomicAdd(&pooled[curg * 128 + 2 * col2], acc.x);
                atomicAdd(&pooled[curg * 128 + 2 * col2 + 1], acc.y);
            }
            acc = make_float2(0.f, 0.f);
            curg = g;
        }
        float2 m = h2[(size_t)(row0 + i) * 64 + col2];
        acc.x += m.x; acc.y += m.y;
    }
    if (curg >= 0) {
        atomicAdd(&pooled[curg * 128 + 2 * col2], acc.x);
        atomicAdd(&pooled[curg * 128 + 2 * col2 + 1], acc.y);
    }
}

// ---------- pooling stage 2: mean + linear head ----------

__global__ __launch_bounds__(256) void k_head(const float* __restrict__ pooled,
                                              const int* __restrict__ batch,
                                              const float* __restrict__ Wl,
                                              const float* __restrict__ bl_,
                                              float* __restrict__ out) {
    int g = blockIdx.x, t = threadIdx.x;
    __shared__ int se[2];
    __shared__ float pm[128];
    __shared__ float part[256];
    if (t < 2) {
        int target = g + t;
        int lo = 0, hi = NN;
        while (lo < hi) {
            int mid = (lo + hi) >> 1;
            if (batch[mid] < target) lo = mid + 1; else hi = mid;
        }
        se[t] = lo;
    }
    __syncthreads();
    int cntg = se[1] - se[0];
    float inv = 1.f / (float)(cntg > 0 ? cntg : 1);
    if (t < 128) pm[t] = pooled[g * 128 + t] * inv;
    __syncthreads();
    int col = t & 63, kh = t >> 6;
    float o = 0.f;
    for (int k = kh * 32; k < kh * 32 + 32; ++k) o += pm[k] * Wl[k * OD + col];
    part[t] = o; __syncthreads();
    if (t < OD)
        out[g * OD + t] = part[t] + part[t + 64] + part[t + 128] + part[t + 192] + bl_[t];
}

// ---------- launcher ----------

extern "C" void kernel_launch(void* const* d_in, const int* in_sizes, int n_in,
                              void* d_out, int out_size, void* d_ws, size_t ws_size,
                              hipStream_t stream) {
    const float* x   = (const float*)d_in[0];
    const int*   ei  = (const int*)d_in[1];
    const int*   bat = (const int*)d_in[2];
    const float* W1  = (const float*)d_in[3];
    const float* b1  = (const float*)d_in[4];
    const float* W2  = (const float*)d_in[5];
    const float* b2  = (const float*)d_in[6];
    const float* Wl  = (const float*)d_in[7];
    const float* bl  = (const float*)d_in[8];
    float* out = (float*)d_out;
    const int* src = ei;
    const int* dst = ei + NE;

    char* w = (char*)d_ws;
    size_t off = 0;
    auto alloc = [&](size_t bytes) -> char* {
        char* p = w + off;
        off = (off + bytes + 255) & ~(size_t)255;
        return p;
    };
    int*   cnt         = (int*)alloc(NN * 4);
    float* dinv        = (float*)alloc(NN * 4);
    int*   bucket_cnt  = (int*)alloc(NBUCK * 4);
    int*   bucket_base = (int*)alloc((NBUCK + 1) * 4);
    int*   bucket_fill = (int*)alloc(NBUCK * 4);
    float* pooled      = (float*)alloc(NG * HD * 4);
    uint32* grec       = (uint32*)alloc((size_t)NE * 4);
    u16*   hp          = (u16*)alloc((size_t)NN * HD * 2);   // bf16 h'
    float* bufB        = (float*)alloc((size_t)NN * HD * 4); // fp32 layer output

    hipMemsetAsync(cnt, 0, NN * 4, stream);
    hipMemsetAsync(bucket_cnt, 0, NBUCK * 4, stream);
    hipMemsetAsync(pooled, 0, NG * HD * 4, stream);

    k_hist<<<SBLOCKS, 256, 0, stream>>>(dst, cnt, bucket_cnt);
    k_dinv<<<(NN + 255) / 256, 256, 0, stream>>>(cnt, dinv);
    k_bscan<<<1, 256, 0, stream>>>(bucket_cnt, bucket_base, bucket_fill);
    k_scatter<<<SBLOCKS, 256, 0, stream>>>(src, dst, bucket_fill, grec);

    // conv1: hp = bf16((x@W1)*dinv) ; bucketed agg + bias + relu -> bufB (fp32)
    k_gemm<<<512, 256, 0, stream>>>(x, W1, dinv, hp, NN);
    k_agg_b<<<NAGG, 512, 0, stream>>>(grec, bucket_base, hp, dinv, b1, bufB);
    // conv2
    k_gemm<<<512, 256, 0, stream>>>(bufB, W2, dinv, hp, NN);
    k_agg_b<<<NAGG, 512, 0, stream>>>(grec, bucket_base, hp, dinv, b2, bufB);
    // pool: segment-sum then mean+head
    k_pool1<<<(NN + POOL_ROWS - 1) / POOL_ROWS, 256, 0, stream>>>(bufB, bat, pooled);
    k_head<<<NG, 256, 0, stream>>>(pooled, bat, Wl, bl, out);
}

// Round 5
// 223.884 us; speedup vs baseline: 6.9798x; 6.9798x over previous
//
#include <hip/hip_runtime.h>
#include <hip/hip_bf16.h>
#include <cstdint>

#define NN 50000
#define NE 800000
#define HD 128
#define OD 64
#define NG 64
#define POOL_ROWS 256
#define NBUCK 196          // ceil(50000/256) coarse buckets of 256 dst
#define SCHUNK 4096        // edges per hist/scatter block
#define SBLOCKS 196        // ceil(800000/4096)
#define CSR_CAP 5120       // per-bucket record capacity (mean 4096, +16 sigma)

typedef unsigned int uint32;
typedef unsigned short u16;

// round-to-nearest-even f32 -> bf16 bits
static __device__ __forceinline__ u16 f2bf(float f) {
    uint32 u = __float_as_uint(f);
    u += 0x7fffu + ((u >> 16) & 1u);
    return (u16)(u >> 16);
}
static __device__ __forceinline__ float bf2f(u16 h) {
    return __uint_as_float(((uint32)h) << 16);
}
static __device__ __forceinline__ void acc_bf2(float2& a, uint32 u) {
    a.x += __uint_as_float(u << 16);
    a.y += __uint_as_float(u & 0xffff0000u);
}

// ---------- bucket histogram (LDS only, no global per-node atomics) ----------

__global__ __launch_bounds__(256) void k_hist(const int* __restrict__ dst,
                                              int* __restrict__ bucket_cnt) {
    __shared__ int lh[256];
    int t = threadIdx.x;
    lh[t] = 0;
    __syncthreads();
    int e0 = blockIdx.x * SCHUNK;
    int ne = min(SCHUNK, NE - e0);
    for (int k = 0; k < 16; ++k) {
        int i = k * 256 + t;
        if (i < ne) atomicAdd(&lh[dst[e0 + i] >> 8], 1);
    }
    __syncthreads();
    if (t < NBUCK && lh[t]) atomicAdd(&bucket_cnt[t], lh[t]);
}

// ---------- bucket exclusive scan (1 block) ----------

__global__ __launch_bounds__(256) void k_bscan(const int* __restrict__ bucket_cnt,
                                               int* __restrict__ bucket_base,
                                               int* __restrict__ bucket_fill,
                                               int* __restrict__ row_start) {
    __shared__ int s[256];
    int t = threadIdx.x;
    int v = (t < NBUCK) ? bucket_cnt[t] : 0;
    s[t] = v; __syncthreads();
    for (int off = 1; off < 256; off <<= 1) {
        int u = (t >= off) ? s[t - off] : 0;
        __syncthreads();
        s[t] += u;
        __syncthreads();
    }
    int excl = s[t] - v;
    if (t < NBUCK) { bucket_base[t] = excl; bucket_fill[t] = excl; }
    if (t == NBUCK - 1) { bucket_base[NBUCK] = s[t]; row_start[NN] = s[t]; }
}

// ---------- bucketed scatter of packed edge records, coalesced via LDS reorder ----------

__global__ __launch_bounds__(256) void k_scatter(const int* __restrict__ src,
                                                 const int* __restrict__ dst,
                                                 int* __restrict__ bucket_fill,
                                                 uint32* __restrict__ grec) {
    __shared__ uint32 rin[SCHUNK];
    __shared__ uint32 rout[SCHUNK];
    __shared__ int lh[256], ls[256], lf[256], lgb[256];
    int t = threadIdx.x;
    lh[t] = 0; lf[t] = 0;
    __syncthreads();
    int e0 = blockIdx.x * SCHUNK;
    int ne = min(SCHUNK, NE - e0);
    for (int k = 0; k < 16; ++k) {
        int i = k * 256 + t;
        if (i < ne) {
            uint32 rec = ((uint32)dst[e0 + i] << 16) | (uint32)src[e0 + i];
            rin[i] = rec;
            atomicAdd(&lh[rec >> 24], 1);
        }
    }
    __syncthreads();
    int v = lh[t];
    ls[t] = v; __syncthreads();
    for (int off = 1; off < 256; off <<= 1) {
        int u = (t >= off) ? ls[t - off] : 0;
        __syncthreads();
        ls[t] += u;
        __syncthreads();
    }
    int excl = ls[t] - v;
    __syncthreads();
    ls[t] = excl;
    if (t < NBUCK && v > 0) lgb[t] = atomicAdd(&bucket_fill[t], v);
    __syncthreads();
    for (int k = 0; k < 16; ++k) {
        int i = k * 256 + t;
        if (i < ne) {
            uint32 rec = rin[i];
            int b = rec >> 24;
            int p = ls[b] + atomicAdd(&lf[b], 1);
            rout[p] = rec;
        }
    }
    __syncthreads();
    for (int k = 0; k < 16; ++k) {
        int i = k * 256 + t;
        if (i < ne) {
            uint32 rec = rout[i];
            int b = rec >> 24;
            grec[lgb[b] + (i - ls[b])] = rec;
        }
    }
}

// ---------- per-bucket counting sort -> u16 CSR + row_start + dinv ----------

__global__ __launch_bounds__(256) void k_csr(const uint32* __restrict__ grec,
                                             const int* __restrict__ bucket_base,
                                             int* __restrict__ row_start,
                                             float* __restrict__ dinv,
                                             u16* __restrict__ csr) {
    __shared__ uint32 rin[CSR_CAP];    // 20 KB
    __shared__ u16 sorted[CSR_CAP];    // 10 KB
    __shared__ int cnt_l[256], off_l[256], fill_l[256];
    const int b = blockIdx.x, t = threadIdx.x;
    const int s0 = bucket_base[b], s1 = bucket_base[b + 1];
    const int n = s1 - s0;
    cnt_l[t] = 0; fill_l[t] = 0;
    __syncthreads();
    for (int i = t; i < n; i += 256) {
        uint32 r = grec[s0 + i];
        if (i < CSR_CAP) rin[i] = r;
        atomicAdd(&cnt_l[(r >> 16) & 255], 1);
    }
    __syncthreads();
    int v = cnt_l[t];
    off_l[t] = v; __syncthreads();
    for (int off = 1; off < 256; off <<= 1) {
        int u = (t >= off) ? off_l[t - off] : 0;
        __syncthreads();
        off_l[t] += u;
        __syncthreads();
    }
    int excl = off_l[t] - v;
    __syncthreads();
    off_l[t] = excl;
    int vtx = (b << 8) + t;
    if (vtx < NN) {
        row_start[vtx] = s0 + excl;
        dinv[vtx] = rsqrtf((float)(v + 1));   // +1 self-loop
    }
    __syncthreads();
    for (int i = t; i < n; i += 256) {
        uint32 r = (i < CSR_CAP) ? rin[i] : grec[s0 + i];
        int d = (r >> 16) & 255;
        int p = off_l[d] + atomicAdd(&fill_l[d], 1);
        u16 sv = (u16)(r & 0xffffu);
        if (p < CSR_CAP) sorted[p] = sv;
        else csr[s0 + p] = sv;                 // overflow fallback (statistically never)
    }
    __syncthreads();
    int m = min(n, CSR_CAP);
    for (int i = t; i < m; i += 256) csr[s0 + i] = sorted[i];
}

// ---------- GEMM: hp[r] = bf16( (X[r] @ W) * dinv[r] ),  X [nrows][128] fp32 ----------

__global__ __launch_bounds__(256, 2) void k_gemm(const float* __restrict__ X,
                                                 const float* __restrict__ W,
                                                 const float* __restrict__ dinv,
                                                 u16* __restrict__ out, int nrows) {
    __shared__ float wl[128 * 128];   // 64 KB
    __shared__ float xl[32 * 128];    // 16 KB
    {
        float4* wl4 = (float4*)wl;
        const float4* W4 = (const float4*)W;
        for (int i = threadIdx.x; i < 128 * 32; i += 256) wl4[i] = W4[i];
    }
    const int rg = threadIdx.x >> 5;
    const int cg = threadIdx.x & 31;
    const int ntiles = (nrows + 31) >> 5;
    for (int tile = blockIdx.x; tile < ntiles; tile += gridDim.x) {
        const int row0 = tile << 5;
        __syncthreads();
        for (int i = threadIdx.x; i < 32 * 32; i += 256) {
            int rr = row0 + (i >> 5);
            ((float4*)xl)[i] = (rr < nrows) ? ((const float4*)X)[rr * 32 + (i & 31)]
                                            : make_float4(0.f, 0.f, 0.f, 0.f);
        }
        __syncthreads();
        float acc[4][4];
#pragma unroll
        for (int a = 0; a < 4; ++a)
#pragma unroll
            for (int b = 0; b < 4; ++b) acc[a][b] = 0.f;
        const float4* wl4 = (const float4*)wl;
        const float4* xl4 = (const float4*)xl;
#pragma unroll 4
        for (int kq = 0; kq < 32; ++kq) {
            float4 w0 = wl4[(4 * kq + 0) * 32 + cg];
            float4 w1 = wl4[(4 * kq + 1) * 32 + cg];
            float4 w2 = wl4[(4 * kq + 2) * 32 + cg];
            float4 w3 = wl4[(4 * kq + 3) * 32 + cg];
#pragma unroll
            for (int r = 0; r < 4; ++r) {
                float4 xv = xl4[(rg * 4 + r) * 32 + kq];
                acc[r][0] += xv.x * w0.x + xv.y * w1.x + xv.z * w2.x + xv.w * w3.x;
                acc[r][1] += xv.x * w0.y + xv.y * w1.y + xv.z * w2.y + xv.w * w3.y;
                acc[r][2] += xv.x * w0.z + xv.y * w1.z + xv.z * w2.z + xv.w * w3.z;
                acc[r][3] += xv.x * w0.w + xv.y * w1.w + xv.z * w2.w + xv.w * w3.w;
            }
        }
#pragma unroll
        for (int r = 0; r < 4; ++r) {
            int rr = row0 + rg * 4 + r;
            if (rr < nrows) {
                float dv = dinv[rr];
                ushort4 o;
                o.x = f2bf(acc[r][0] * dv);
                o.y = f2bf(acc[r][1] * dv);
                o.z = f2bf(acc[r][2] * dv);
                o.w = f2bf(acc[r][3] * dv);
                ((ushort4*)out)[(size_t)rr * 32 + cg] = o;
            }
        }
    }
}

// ---------- aggregation: out[v] = relu(dinv[v]*(hp[v] + sum_{s->v} hp[s]) + b) ----------
// hp is bf16 [NN][128]; each lane reads one uint = 2 bf16 (cols 2*lane, 2*lane+1).

__global__ void k_agg(const uint32* __restrict__ hp, const int* __restrict__ row_start,
                      const u16* __restrict__ csr, const float* __restrict__ dinv,
                      const float* __restrict__ bias, float* __restrict__ out) {
    int wid = threadIdx.x >> 6, lane = threadIdx.x & 63;
    int v = blockIdx.x * 4 + wid;
    if (v >= NN) return;
    float2 acc = make_float2(0.f, 0.f);
    acc_bf2(acc, hp[(size_t)v * 64 + lane]);   // self loop
    int beg = row_start[v], end = row_start[v + 1];
    int e = beg;
    // 4 independent row-gathers in flight (latency hiding)
    for (; e + 4 <= end; e += 4) {
        int s0 = csr[e], s1 = csr[e + 1], s2 = csr[e + 2], s3 = csr[e + 3];
        uint32 m0 = hp[(size_t)s0 * 64 + lane];
        uint32 m1 = hp[(size_t)s1 * 64 + lane];
        uint32 m2 = hp[(size_t)s2 * 64 + lane];
        uint32 m3 = hp[(size_t)s3 * 64 + lane];
        acc_bf2(acc, m0); acc_bf2(acc, m1); acc_bf2(acc, m2); acc_bf2(acc, m3);
    }
    for (; e < end; ++e) {
        acc_bf2(acc, hp[(size_t)csr[e] * 64 + lane]);
    }
    float dv = dinv[v];
    float2 bb = ((const float2*)bias)[lane];
    float2 o;
    o.x = fmaxf(acc.x * dv + bb.x, 0.f);
    o.y = fmaxf(acc.y * dv + bb.y, 0.f);
    ((float2*)out)[(size_t)v * 64 + lane] = o;
}

// ---------- pooling stage 1: node-parallel segment-sum into pooled[64][128] ----------

__global__ __launch_bounds__(256) void k_pool1(const float* __restrict__ h,
                                               const int* __restrict__ batch,
                                               float* __restrict__ pooled) {
    __shared__ int bl[POOL_ROWS];
    const int row0 = blockIdx.x * POOL_ROWS;
    const int rend = min(row0 + POOL_ROWS, NN);
    const int nrows = rend - row0;
    for (int i = threadIdx.x; i < nrows; i += 256) bl[i] = batch[row0 + i];
    __syncthreads();
    const int col2 = threadIdx.x & 63;
    const int rp   = threadIdx.x >> 6;
    const float2* h2 = (const float2*)h;
    float2 acc = make_float2(0.f, 0.f);
    int curg = -1;
    for (int i = rp; i < nrows; i += 4) {
        int g = bl[i];
        if (g != curg) {
            if (curg >= 0) {
                atomicAdd(&pooled[curg * 128 + 2 * col2], acc.x);
                atomicAdd(&pooled[curg * 128 + 2 * col2 + 1], acc.y);
            }
            acc = make_float2(0.f, 0.f);
            curg = g;
        }
        float2 m = h2[(size_t)(row0 + i) * 64 + col2];
        acc.x += m.x; acc.y += m.y;
    }
    if (curg >= 0) {
        atomicAdd(&pooled[curg * 128 + 2 * col2], acc.x);
        atomicAdd(&pooled[curg * 128 + 2 * col2 + 1], acc.y);
    }
}

// ---------- pooling stage 2: mean + linear head ----------

__global__ __launch_bounds__(256) void k_head(const float* __restrict__ pooled,
                                              const int* __restrict__ batch,
                                              const float* __restrict__ Wl,
                                              const float* __restrict__ bl_,
                                              float* __restrict__ out) {
    int g = blockIdx.x, t = threadIdx.x;
    __shared__ int se[2];
    __shared__ float pm[128];
    __shared__ float part[256];
    if (t < 2) {
        int target = g + t;
        int lo = 0, hi = NN;
        while (lo < hi) {
            int mid = (lo + hi) >> 1;
            if (batch[mid] < target) lo = mid + 1; else hi = mid;
        }
        se[t] = lo;
    }
    __syncthreads();
    int cntg = se[1] - se[0];
    float inv = 1.f / (float)(cntg > 0 ? cntg : 1);
    if (t < 128) pm[t] = pooled[g * 128 + t] * inv;
    __syncthreads();
    int col = t & 63, kh = t >> 6;
    float o = 0.f;
    for (int k = kh * 32; k < kh * 32 + 32; ++k) o += pm[k] * Wl[k * OD + col];
    part[t] = o; __syncthreads();
    if (t < OD)
        out[g * OD + t] = part[t] + part[t + 64] + part[t + 128] + part[t + 192] + bl_[t];
}

// ---------- launcher ----------

extern "C" void kernel_launch(void* const* d_in, const int* in_sizes, int n_in,
                              void* d_out, int out_size, void* d_ws, size_t ws_size,
                              hipStream_t stream) {
    const float* x   = (const float*)d_in[0];
    const int*   ei  = (const int*)d_in[1];
    const int*   bat = (const int*)d_in[2];
    const float* W1  = (const float*)d_in[3];
    const float* b1  = (const float*)d_in[4];
    const float* W2  = (const float*)d_in[5];
    const float* b2  = (const float*)d_in[6];
    const float* Wl  = (const float*)d_in[7];
    const float* bl  = (const float*)d_in[8];
    float* out = (float*)d_out;
    const int* src = ei;
    const int* dst = ei + NE;

    char* w = (char*)d_ws;
    size_t off = 0;
    auto alloc = [&](size_t bytes) -> char* {
        char* p = w + off;
        off = (off + bytes + 255) & ~(size_t)255;
        return p;
    };
    float* dinv        = (float*)alloc(NN * 4);
    int*   row_start   = (int*)alloc((NN + 1) * 4);
    int*   bucket_cnt  = (int*)alloc(NBUCK * 4);
    int*   bucket_base = (int*)alloc((NBUCK + 1) * 4);
    int*   bucket_fill = (int*)alloc(NBUCK * 4);
    float* pooled      = (float*)alloc(NG * HD * 4);
    uint32* grec       = (uint32*)alloc((size_t)NE * 4);
    u16*   csr         = (u16*)alloc((size_t)NE * 2);
    u16*   hp          = (u16*)alloc((size_t)NN * HD * 2);   // bf16 h'
    float* bufB        = (float*)alloc((size_t)NN * HD * 4); // fp32 layer output

    hipMemsetAsync(bucket_cnt, 0, NBUCK * 4, stream);
    hipMemsetAsync(pooled, 0, NG * HD * 4, stream);

    k_hist<<<SBLOCKS, 256, 0, stream>>>(dst, bucket_cnt);
    k_bscan<<<1, 256, 0, stream>>>(bucket_cnt, bucket_base, bucket_fill, row_start);
    k_scatter<<<SBLOCKS, 256, 0, stream>>>(src, dst, bucket_fill, grec);
    k_csr<<<NBUCK, 256, 0, stream>>>(grec, bucket_base, row_start, dinv, csr);

    // conv1: hp = bf16((x@W1)*dinv) ; agg + bias + relu -> bufB (fp32)
    k_gemm<<<512, 256, 0, stream>>>(x, W1, dinv, hp, NN);
    k_agg<<<(NN + 3) / 4, 256, 0, stream>>>((const uint32*)hp, row_start, csr, dinv, b1, bufB);
    // conv2
    k_gemm<<<512, 256, 0, stream>>>(bufB, W2, dinv, hp, NN);
    k_agg<<<(NN + 3) / 4, 256, 0, stream>>>((const uint32*)hp, row_start, csr, dinv, b2, bufB);
    // pool: segment-sum then mean+head
    k_pool1<<<(NN + POOL_ROWS - 1) / POOL_ROWS, 256, 0, stream>>>(bufB, bat, pooled);
    k_head<<<NG, 256, 0, stream>>>(pooled, bat, Wl, bl, out);
}

// Round 6
// 179.666 us; speedup vs baseline: 8.6976x; 1.2461x over previous
//
#include <hip/hip_runtime.h>
#include <hip/hip_bf16.h>
#include <cstdint>

#define NN 50000
#define NE 800000
#define HD 128
#define OD 64
#define NG 64
#define POOL_ROWS 256
#define NBUCK 196          // ceil(50000/256) coarse buckets of 256 dst
#define SCHUNK 4096        // edges per hist/scatter block
#define SBLOCKS 196        // ceil(800000/4096)
#define CSR_CAP 5120       // per-bucket record capacity
#define GEMM_BLOCKS 782    // ceil(50000/64)

typedef unsigned int uint32;
typedef unsigned short u16;
typedef _Float16 f16;
typedef _Float16 f16x8 __attribute__((ext_vector_type(8)));
typedef float f32x4 __attribute__((ext_vector_type(4)));

// round-to-nearest-even f32 -> bf16 bits
static __device__ __forceinline__ u16 f2bf(float f) {
    uint32 u = __float_as_uint(f);
    u += 0x7fffu + ((u >> 16) & 1u);
    return (u16)(u >> 16);
}
static __device__ __forceinline__ float bf2f(u16 h) {
    return __uint_as_float(((uint32)h) << 16);
}
static __device__ __forceinline__ void acc_bf2(float2& a, uint32 u) {
    a.x += __uint_as_float(u << 16);
    a.y += __uint_as_float(u & 0xffff0000u);
}
static __device__ __forceinline__ u16 f2h(float f) {
    f16 h = (f16)f;                       // v_cvt_f16_f32, RTNE
    return __builtin_bit_cast(u16, h);
}
// epilogue LDS transpose swizzle (involution, 16B-granular)
static __device__ __forceinline__ int swz(int row) {
    return ((row & 7) << 4) | ((row & 8) << 3);
}

// ---------- bucket histogram (LDS only) ----------

__global__ __launch_bounds__(256) void k_hist(const int* __restrict__ dst,
                                              int* __restrict__ bucket_cnt) {
    __shared__ int lh[256];
    int t = threadIdx.x;
    lh[t] = 0;
    __syncthreads();
    int e0 = blockIdx.x * SCHUNK;
    int ne = min(SCHUNK, NE - e0);
    for (int k = 0; k < 16; ++k) {
        int i = k * 256 + t;
        if (i < ne) atomicAdd(&lh[dst[e0 + i] >> 8], 1);
    }
    __syncthreads();
    if (t < NBUCK && lh[t]) atomicAdd(&bucket_cnt[t], lh[t]);
}

// ---------- bucket exclusive scan (1 block) ----------

__global__ __launch_bounds__(256) void k_bscan(const int* __restrict__ bucket_cnt,
                                               int* __restrict__ bucket_base,
                                               int* __restrict__ bucket_fill,
                                               int* __restrict__ row_start) {
    __shared__ int s[256];
    int t = threadIdx.x;
    int v = (t < NBUCK) ? bucket_cnt[t] : 0;
    s[t] = v; __syncthreads();
    for (int off = 1; off < 256; off <<= 1) {
        int u = (t >= off) ? s[t - off] : 0;
        __syncthreads();
        s[t] += u;
        __syncthreads();
    }
    int excl = s[t] - v;
    if (t < NBUCK) { bucket_base[t] = excl; bucket_fill[t] = excl; }
    if (t == NBUCK - 1) { bucket_base[NBUCK] = s[t]; row_start[NN] = s[t]; }
}

// ---------- bucketed scatter of packed edge records ----------

__global__ __launch_bounds__(256) void k_scatter(const int* __restrict__ src,
                                                 const int* __restrict__ dst,
                                                 int* __restrict__ bucket_fill,
                                                 uint32* __restrict__ grec) {
    __shared__ uint32 rin[SCHUNK];
    __shared__ uint32 rout[SCHUNK];
    __shared__ int lh[256], ls[256], lf[256], lgb[256];
    int t = threadIdx.x;
    lh[t] = 0; lf[t] = 0;
    __syncthreads();
    int e0 = blockIdx.x * SCHUNK;
    int ne = min(SCHUNK, NE - e0);
    for (int k = 0; k < 16; ++k) {
        int i = k * 256 + t;
        if (i < ne) {
            uint32 rec = ((uint32)dst[e0 + i] << 16) | (uint32)src[e0 + i];
            rin[i] = rec;
            atomicAdd(&lh[rec >> 24], 1);
        }
    }
    __syncthreads();
    int v = lh[t];
    ls[t] = v; __syncthreads();
    for (int off = 1; off < 256; off <<= 1) {
        int u = (t >= off) ? ls[t - off] : 0;
        __syncthreads();
        ls[t] += u;
        __syncthreads();
    }
    int excl = ls[t] - v;
    __syncthreads();
    ls[t] = excl;
    if (t < NBUCK && v > 0) lgb[t] = atomicAdd(&bucket_fill[t], v);
    __syncthreads();
    for (int k = 0; k < 16; ++k) {
        int i = k * 256 + t;
        if (i < ne) {
            uint32 rec = rin[i];
            int b = rec >> 24;
            int p = ls[b] + atomicAdd(&lf[b], 1);
            rout[p] = rec;
        }
    }
    __syncthreads();
    for (int k = 0; k < 16; ++k) {
        int i = k * 256 + t;
        if (i < ne) {
            uint32 rec = rout[i];
            int b = rec >> 24;
            grec[lgb[b] + (i - ls[b])] = rec;
        }
    }
}

// ---------- per-bucket counting sort -> u16 CSR + row_start + dinv ----------

__global__ __launch_bounds__(256) void k_csr(const uint32* __restrict__ grec,
                                             const int* __restrict__ bucket_base,
                                             int* __restrict__ row_start,
                                             float* __restrict__ dinv,
                                             u16* __restrict__ csr) {
    __shared__ uint32 rin[CSR_CAP];
    __shared__ u16 sorted[CSR_CAP];
    __shared__ int cnt_l[256], off_l[256], fill_l[256];
    const int b = blockIdx.x, t = threadIdx.x;
    const int s0 = bucket_base[b], s1 = bucket_base[b + 1];
    const int n = s1 - s0;
    cnt_l[t] = 0; fill_l[t] = 0;
    __syncthreads();
    for (int i = t; i < n; i += 256) {
        uint32 r = grec[s0 + i];
        if (i < CSR_CAP) rin[i] = r;
        atomicAdd(&cnt_l[(r >> 16) & 255], 1);
    }
    __syncthreads();
    int v = cnt_l[t];
    off_l[t] = v; __syncthreads();
    for (int off = 1; off < 256; off <<= 1) {
        int u = (t >= off) ? off_l[t - off] : 0;
        __syncthreads();
        off_l[t] += u;
        __syncthreads();
    }
    int excl = off_l[t] - v;
    __syncthreads();
    off_l[t] = excl;
    int vtx = (b << 8) + t;
    if (vtx < NN) {
        row_start[vtx] = s0 + excl;
        dinv[vtx] = rsqrtf((float)(v + 1));
    }
    __syncthreads();
    for (int i = t; i < n; i += 256) {
        uint32 r = (i < CSR_CAP) ? rin[i] : grec[s0 + i];
        int d = (r >> 16) & 255;
        int p = off_l[d] + atomicAdd(&fill_l[d], 1);
        u16 sv = (u16)(r & 0xffffu);
        if (p < CSR_CAP) sorted[p] = sv;
        else csr[s0 + p] = sv;
    }
    __syncthreads();
    int m = min(n, CSR_CAP);
    for (int i = t; i < m; i += 256) csr[s0 + i] = sorted[i];
}

// ---------- W pre-pack: fp16 fragment order [ks][ct][lane][8] ----------
// slot map sigma: k = ks*32 + (lane>>4)*8 + j ; n = ct*16 + (lane&15)
// (A and B packed with the same sigma -> contraction correct for any bijection)

__global__ __launch_bounds__(256) void k_packW(const float* __restrict__ W,
                                               u16* __restrict__ pw) {
    int tau = blockIdx.x * 256 + threadIdx.x;   // 0..2047
    int lane = tau & 63, ct = (tau >> 6) & 7, ks = (tau >> 9) & 3;
    int g = lane >> 4, n = ct * 16 + (lane & 15);
    uint32 pk[4];
#pragma unroll
    for (int jp = 0; jp < 4; ++jp) {
        int k = ks * 32 + g * 8 + jp * 2;
        uint32 lo = f2h(W[k * 128 + n]);
        uint32 hi = f2h(W[(k + 1) * 128 + n]);
        pk[jp] = lo | (hi << 16);
    }
    uint4 val = make_uint4(pk[0], pk[1], pk[2], pk[3]);
    ((uint4*)pw)[(size_t)(((ks * 8 + ct) * 64 + lane))] = val;
}

// ---------- MFMA GEMM: hp[r] = bf16( (X[r] @ W) * dinv[r] ) ----------
// block = 64 rows x 128 cols, 4 waves (one 16-row band each)

__global__ __launch_bounds__(256, 2) void k_gemm_mfma(const float* __restrict__ X,
                                                      const u16* __restrict__ pw,
                                                      const float* __restrict__ dinv,
                                                      u16* __restrict__ hp, int nrows) {
    __shared__ u16 xp[8192];    // 16 KB: A-frags [ks][wv][lane][8], reused for epilogue
    const int t = threadIdx.x, lane = t & 63, wv = t >> 6;
    const int r0 = blockIdx.x * 64;
    const float4* X4 = (const float4*)X;

    // stage X-tile as fp16 A-frags
#pragma unroll
    for (int it = 0; it < 8; ++it) {
        int idx = it * 256 + t;          // 64 rows x 32 float4-cols
        int rloc = idx >> 5, kq = idx & 31;
        int rr = r0 + rloc;
        float4 xv = (rr < nrows) ? X4[(size_t)rr * 32 + kq]
                                 : make_float4(0.f, 0.f, 0.f, 0.f);
        int ks = kq >> 3, g = (kq >> 1) & 3, half = kq & 1;
        int wvd = rloc >> 4, ln = (rloc & 15) + 16 * g;
        ushort4 p;
        p.x = f2h(xv.x); p.y = f2h(xv.y); p.z = f2h(xv.z); p.w = f2h(xv.w);
        *(ushort4*)&xp[(((ks * 4 + wvd) * 64 + ln) << 3) + half * 4] = p;
    }
    __syncthreads();

    f32x4 acc[8];
#pragma unroll
    for (int c = 0; c < 8; ++c) acc[c] = (f32x4){0.f, 0.f, 0.f, 0.f};

#pragma unroll
    for (int ks = 0; ks < 4; ++ks) {
        f16x8 a = *reinterpret_cast<f16x8*>(&xp[((ks * 4 + wv) * 64 + lane) << 3]);
#pragma unroll
        for (int ct = 0; ct < 8; ++ct) {
            f16x8 b = *reinterpret_cast<const f16x8*>(pw + ((size_t)((ks * 8 + ct) * 64 + lane) << 3));
            acc[ct] = __builtin_amdgcn_mfma_f32_16x16x32_f16(a, b, acc[ct], 0, 0, 0);
        }
    }

    // epilogue: *dinv, ->bf16, swizzled LDS transpose, coalesced store
    float dv[4];
#pragma unroll
    for (int r = 0; r < 4; ++r) {
        int m = r0 + wv * 16 + 4 * (lane >> 4) + r;
        dv[r] = (m < nrows) ? dinv[m] : 0.f;
    }
    __syncthreads();   // xp free
#pragma unroll
    for (int ct = 0; ct < 8; ++ct)
#pragma unroll
        for (int r = 0; r < 4; ++r) {
            int row_local = wv * 16 + 4 * (lane >> 4) + r;
            int colb = ct * 32 + (lane & 15) * 2;
            int byte = row_local * 256 + (colb ^ swz(row_local));
            xp[byte >> 1] = f2bf(acc[ct][r] * dv[r]);
        }
    __syncthreads();
#pragma unroll
    for (int p = 0; p < 4; ++p) {
        int row_local = t >> 2;
        int chunk = (t & 3) + 4 * p;
        int byte = row_local * 256 + ((chunk * 16) ^ swz(row_local));
        uint4 val = *reinterpret_cast<uint4*>(&xp[byte >> 1]);
        int rr = r0 + row_local;
        if (rr < nrows) ((uint4*)hp)[(size_t)rr * 16 + chunk] = val;
    }
}

// ---------- aggregation: out[v] = relu(dinv[v]*(hp[v] + sum_{s->v} hp[s]) + b) ----------

__global__ void k_agg(const uint32* __restrict__ hp, const int* __restrict__ row_start,
                      const u16* __restrict__ csr, const float* __restrict__ dinv,
                      const float* __restrict__ bias, float* __restrict__ out) {
    int wid = threadIdx.x >> 6, lane = threadIdx.x & 63;
    int v = blockIdx.x * 4 + wid;
    if (v >= NN) return;
    float2 acc = make_float2(0.f, 0.f);
    acc_bf2(acc, hp[(size_t)v * 64 + lane]);   // self loop
    int beg = row_start[v], end = row_start[v + 1];
    int e = beg;
    for (; e + 4 <= end; e += 4) {
        int s0 = csr[e], s1 = csr[e + 1], s2 = csr[e + 2], s3 = csr[e + 3];
        uint32 m0 = hp[(size_t)s0 * 64 + lane];
        uint32 m1 = hp[(size_t)s1 * 64 + lane];
        uint32 m2 = hp[(size_t)s2 * 64 + lane];
        uint32 m3 = hp[(size_t)s3 * 64 + lane];
        acc_bf2(acc, m0); acc_bf2(acc, m1); acc_bf2(acc, m2); acc_bf2(acc, m3);
    }
    for (; e < end; ++e) {
        acc_bf2(acc, hp[(size_t)csr[e] * 64 + lane]);
    }
    float dvv = dinv[v];
    float2 bb = ((const float2*)bias)[lane];
    float2 o;
    o.x = fmaxf(acc.x * dvv + bb.x, 0.f);
    o.y = fmaxf(acc.y * dvv + bb.y, 0.f);
    ((float2*)out)[(size_t)v * 64 + lane] = o;
}

// ---------- pooling stage 1 ----------

__global__ __launch_bounds__(256) void k_pool1(const float* __restrict__ h,
                                               const int* __restrict__ batch,
                                               float* __restrict__ pooled) {
    __shared__ int bl[POOL_ROWS];
    const int row0 = blockIdx.x * POOL_ROWS;
    const int rend = min(row0 + POOL_ROWS, NN);
    const int nrows = rend - row0;
    for (int i = threadIdx.x; i < nrows; i += 256) bl[i] = batch[row0 + i];
    __syncthreads();
    const int col2 = threadIdx.x & 63;
    const int rp   = threadIdx.x >> 6;
    const float2* h2 = (const float2*)h;
    float2 acc = make_float2(0.f, 0.f);
    int curg = -1;
    for (int i = rp; i < nrows; i += 4) {
        int g = bl[i];
        if (g != curg) {
            if (curg >= 0) {
                atomicAdd(&pooled[curg * 128 + 2 * col2], acc.x);
                atomicAdd(&pooled[curg * 128 + 2 * col2 + 1], acc.y);
            }
            acc = make_float2(0.f, 0.f);
            curg = g;
        }
        float2 m = h2[(size_t)(row0 + i) * 64 + col2];
        acc.x += m.x; acc.y += m.y;
    }
    if (curg >= 0) {
        atomicAdd(&pooled[curg * 128 + 2 * col2], acc.x);
        atomicAdd(&pooled[curg * 128 + 2 * col2 + 1], acc.y);
    }
}

// ---------- pooling stage 2: mean + linear head ----------

__global__ __launch_bounds__(256) void k_head(const float* __restrict__ pooled,
                                              const int* __restrict__ batch,
                                              const float* __restrict__ Wl,
                                              const float* __restrict__ bl_,
                                              float* __restrict__ out) {
    int g = blockIdx.x, t = threadIdx.x;
    __shared__ int se[2];
    __shared__ float pm[128];
    __shared__ float part[256];
    if (t < 2) {
        int target = g + t;
        int lo = 0, hi = NN;
        while (lo < hi) {
            int mid = (lo + hi) >> 1;
            if (batch[mid] < target) lo = mid + 1; else hi = mid;
        }
        se[t] = lo;
    }
    __syncthreads();
    int cntg = se[1] - se[0];
    float inv = 1.f / (float)(cntg > 0 ? cntg : 1);
    if (t < 128) pm[t] = pooled[g * 128 + t] * inv;
    __syncthreads();
    int col = t & 63, kh = t >> 6;
    float o = 0.f;
    for (int k = kh * 32; k < kh * 32 + 32; ++k) o += pm[k] * Wl[k * OD + col];
    part[t] = o; __syncthreads();
    if (t < OD)
        out[g * OD + t] = part[t] + part[t + 64] + part[t + 128] + part[t + 192] + bl_[t];
}

// ---------- launcher ----------

extern "C" void kernel_launch(void* const* d_in, const int* in_sizes, int n_in,
                              void* d_out, int out_size, void* d_ws, size_t ws_size,
                              hipStream_t stream) {
    const float* x   = (const float*)d_in[0];
    const int*   ei  = (const int*)d_in[1];
    const int*   bat = (const int*)d_in[2];
    const float* W1  = (const float*)d_in[3];
    const float* b1  = (const float*)d_in[4];
    const float* W2  = (const float*)d_in[5];
    const float* b2  = (const float*)d_in[6];
    const float* Wl  = (const float*)d_in[7];
    const float* bl  = (const float*)d_in[8];
    float* out = (float*)d_out;
    const int* src = ei;
    const int* dst = ei + NE;

    char* w = (char*)d_ws;
    size_t off = 0;
    auto alloc = [&](size_t bytes) -> char* {
        char* p = w + off;
        off = (off + bytes + 255) & ~(size_t)255;
        return p;
    };
    float* dinv        = (float*)alloc(NN * 4);
    int*   row_start   = (int*)alloc((NN + 1) * 4);
    int*   bucket_cnt  = (int*)alloc(NBUCK * 4);
    int*   bucket_base = (int*)alloc((NBUCK + 1) * 4);
    int*   bucket_fill = (int*)alloc(NBUCK * 4);
    float* pooled      = (float*)alloc(NG * HD * 4);
    u16*   pw1         = (u16*)alloc(2048 * 16);   // packed W1 fp16 frags
    u16*   pw2         = (u16*)alloc(2048 * 16);   // packed W2 fp16 frags
    uint32* grec       = (uint32*)alloc((size_t)NE * 4);
    u16*   csr         = (u16*)alloc((size_t)NE * 2);
    u16*   hp          = (u16*)alloc((size_t)NN * HD * 2);   // bf16 h'
    float* bufB        = (float*)alloc((size_t)NN * HD * 4); // fp32 layer output

    hipMemsetAsync(bucket_cnt, 0, NBUCK * 4, stream);
    hipMemsetAsync(pooled, 0, NG * HD * 4, stream);

    k_packW<<<8, 256, 0, stream>>>(W1, pw1);
    k_packW<<<8, 256, 0, stream>>>(W2, pw2);

    k_hist<<<SBLOCKS, 256, 0, stream>>>(dst, bucket_cnt);
    k_bscan<<<1, 256, 0, stream>>>(bucket_cnt, bucket_base, bucket_fill, row_start);
    k_scatter<<<SBLOCKS, 256, 0, stream>>>(src, dst, bucket_fill, grec);
    k_csr<<<NBUCK, 256, 0, stream>>>(grec, bucket_base, row_start, dinv, csr);

    // conv1
    k_gemm_mfma<<<GEMM_BLOCKS, 256, 0, stream>>>(x, pw1, dinv, hp, NN);
    k_agg<<<(NN + 3) / 4, 256, 0, stream>>>((const uint32*)hp, row_start, csr, dinv, b1, bufB);
    // conv2
    k_gemm_mfma<<<GEMM_BLOCKS, 256, 0, stream>>>(bufB, pw2, dinv, hp, NN);
    k_agg<<<(NN + 3) / 4, 256, 0, stream>>>((const uint32*)hp, row_start, csr, dinv, b2, bufB);
    // pool
    k_pool1<<<(NN + POOL_ROWS - 1) / POOL_ROWS, 256, 0, stream>>>(bufB, bat, pooled);
    k_head<<<NG, 256, 0, stream>>>(pooled, bat, Wl, bl, out);
}

// Round 7
// 176.687 us; speedup vs baseline: 8.8443x; 1.0169x over previous
//
#include <hip/hip_runtime.h>
#include <hip/hip_bf16.h>
#include <cstdint>

#define NN 50000
#define NE 800000
#define HD 128
#define OD 64
#define NG 64
#define POOL_ROWS 256
#define NBUCK 196          // ceil(50000/256) coarse buckets of 256 dst
#define SCHUNK 4096        // edges per hist/scatter block
#define SBLOCKS 196        // ceil(800000/4096)
#define CSR_CAP 5120       // per-bucket record capacity
#define GEMM_BLOCKS 782    // ceil(50000/64)

typedef unsigned int uint32;
typedef unsigned short u16;
typedef _Float16 f16;
typedef _Float16 f16x8 __attribute__((ext_vector_type(8)));
typedef float f32x4 __attribute__((ext_vector_type(4)));

// round-to-nearest-even f32 -> bf16 bits
static __device__ __forceinline__ u16 f2bf(float f) {
    uint32 u = __float_as_uint(f);
    u += 0x7fffu + ((u >> 16) & 1u);
    return (u16)(u >> 16);
}
static __device__ __forceinline__ float bf2f(u16 h) {
    return __uint_as_float(((uint32)h) << 16);
}
static __device__ __forceinline__ void acc_bf2(float2& a, uint32 u) {
    a.x += __uint_as_float(u << 16);
    a.y += __uint_as_float(u & 0xffff0000u);
}
static __device__ __forceinline__ u16 f2h(float f) {
    f16 h = (f16)f;                       // v_cvt_f16_f32, RTNE
    return __builtin_bit_cast(u16, h);
}
// epilogue LDS transpose swizzle (involution, 16B-granular)
static __device__ __forceinline__ int swz(int row) {
    return ((row & 7) << 4) | ((row & 8) << 3);
}

// ---------- W pre-pack: fp16 fragment order [ks][ct][lane][8] ----------
// slot map sigma: k = ks*32 + (lane>>4)*8 + j ; n = ct*16 + (lane&15)
// (A and B packed with the same sigma -> contraction correct for any bijection)
// Block 0 additionally zeroes bucket_cnt (replaces hipMemsetAsync in graph).

__global__ __launch_bounds__(256) void k_packW(const float* __restrict__ W,
                                               u16* __restrict__ pw,
                                               int* __restrict__ bucket_cnt) {
    if (blockIdx.x == 0 && threadIdx.x < NBUCK) bucket_cnt[threadIdx.x] = 0;
    int tau = blockIdx.x * 256 + threadIdx.x;   // 0..2047
    int lane = tau & 63, ct = (tau >> 6) & 7, ks = (tau >> 9) & 3;
    int g = lane >> 4, n = ct * 16 + (lane & 15);
    uint32 pk[4];
#pragma unroll
    for (int jp = 0; jp < 4; ++jp) {
        int k = ks * 32 + g * 8 + jp * 2;
        uint32 lo = f2h(W[k * 128 + n]);
        uint32 hi = f2h(W[(k + 1) * 128 + n]);
        pk[jp] = lo | (hi << 16);
    }
    uint4 val = make_uint4(pk[0], pk[1], pk[2], pk[3]);
    ((uint4*)pw)[(size_t)(((ks * 8 + ct) * 64 + lane))] = val;
}

// ---------- bucket histogram (LDS only) ----------

__global__ __launch_bounds__(256) void k_hist(const int* __restrict__ dst,
                                              int* __restrict__ bucket_cnt) {
    __shared__ int lh[256];
    int t = threadIdx.x;
    lh[t] = 0;
    __syncthreads();
    int e0 = blockIdx.x * SCHUNK;
    int ne = min(SCHUNK, NE - e0);
    for (int k = 0; k < 16; ++k) {
        int i = k * 256 + t;
        if (i < ne) atomicAdd(&lh[dst[e0 + i] >> 8], 1);
    }
    __syncthreads();
    if (t < NBUCK && lh[t]) atomicAdd(&bucket_cnt[t], lh[t]);
}

// ---------- bucket exclusive scan (1 block); also zeroes pooled ----------

__global__ __launch_bounds__(256) void k_bscan(const int* __restrict__ bucket_cnt,
                                               int* __restrict__ bucket_base,
                                               int* __restrict__ bucket_fill,
                                               int* __restrict__ row_start,
                                               float* __restrict__ pooled) {
    __shared__ int s[256];
    int t = threadIdx.x;
    // zero pooled[64][128] (replaces hipMemsetAsync in graph)
    float4 z = make_float4(0.f, 0.f, 0.f, 0.f);
#pragma unroll
    for (int i = 0; i < 8; ++i) ((float4*)pooled)[i * 256 + t] = z;
    int v = (t < NBUCK) ? bucket_cnt[t] : 0;
    s[t] = v; __syncthreads();
    for (int off = 1; off < 256; off <<= 1) {
        int u = (t >= off) ? s[t - off] : 0;
        __syncthreads();
        s[t] += u;
        __syncthreads();
    }
    int excl = s[t] - v;
    if (t < NBUCK) { bucket_base[t] = excl; bucket_fill[t] = excl; }
    if (t == NBUCK - 1) { bucket_base[NBUCK] = s[t]; row_start[NN] = s[t]; }
}

// ---------- bucketed scatter of packed edge records ----------

__global__ __launch_bounds__(256) void k_scatter(const int* __restrict__ src,
                                                 const int* __restrict__ dst,
                                                 int* __restrict__ bucket_fill,
                                                 uint32* __restrict__ grec) {
    __shared__ uint32 rin[SCHUNK];
    __shared__ uint32 rout[SCHUNK];
    __shared__ int lh[256], ls[256], lf[256], lgb[256];
    int t = threadIdx.x;
    lh[t] = 0; lf[t] = 0;
    __syncthreads();
    int e0 = blockIdx.x * SCHUNK;
    int ne = min(SCHUNK, NE - e0);
    for (int k = 0; k < 16; ++k) {
        int i = k * 256 + t;
        if (i < ne) {
            uint32 rec = ((uint32)dst[e0 + i] << 16) | (uint32)src[e0 + i];
            rin[i] = rec;
            atomicAdd(&lh[rec >> 24], 1);
        }
    }
    __syncthreads();
    int v = lh[t];
    ls[t] = v; __syncthreads();
    for (int off = 1; off < 256; off <<= 1) {
        int u = (t >= off) ? ls[t - off] : 0;
        __syncthreads();
        ls[t] += u;
        __syncthreads();
    }
    int excl = ls[t] - v;
    __syncthreads();
    ls[t] = excl;
    if (t < NBUCK && v > 0) lgb[t] = atomicAdd(&bucket_fill[t], v);
    __syncthreads();
    for (int k = 0; k < 16; ++k) {
        int i = k * 256 + t;
        if (i < ne) {
            uint32 rec = rin[i];
            int b = rec >> 24;
            int p = ls[b] + atomicAdd(&lf[b], 1);
            rout[p] = rec;
        }
    }
    __syncthreads();
    for (int k = 0; k < 16; ++k) {
        int i = k * 256 + t;
        if (i < ne) {
            uint32 rec = rout[i];
            int b = rec >> 24;
            grec[lgb[b] + (i - ls[b])] = rec;
        }
    }
}

// ---------- per-bucket counting sort -> u16 CSR + row_start + dinv ----------

__global__ __launch_bounds__(256) void k_csr(const uint32* __restrict__ grec,
                                             const int* __restrict__ bucket_base,
                                             int* __restrict__ row_start,
                                             float* __restrict__ dinv,
                                             u16* __restrict__ csr) {
    __shared__ uint32 rin[CSR_CAP];
    __shared__ u16 sorted[CSR_CAP];
    __shared__ int cnt_l[256], off_l[256], fill_l[256];
    const int b = blockIdx.x, t = threadIdx.x;
    const int s0 = bucket_base[b], s1 = bucket_base[b + 1];
    const int n = s1 - s0;
    cnt_l[t] = 0; fill_l[t] = 0;
    __syncthreads();
    for (int i = t; i < n; i += 256) {
        uint32 r = grec[s0 + i];
        if (i < CSR_CAP) rin[i] = r;
        atomicAdd(&cnt_l[(r >> 16) & 255], 1);
    }
    __syncthreads();
    int v = cnt_l[t];
    off_l[t] = v; __syncthreads();
    for (int off = 1; off < 256; off <<= 1) {
        int u = (t >= off) ? off_l[t - off] : 0;
        __syncthreads();
        off_l[t] += u;
        __syncthreads();
    }
    int excl = off_l[t] - v;
    __syncthreads();
    off_l[t] = excl;
    int vtx = (b << 8) + t;
    if (vtx < NN) {
        row_start[vtx] = s0 + excl;
        dinv[vtx] = rsqrtf((float)(v + 1));
    }
    __syncthreads();
    for (int i = t; i < n; i += 256) {
        uint32 r = (i < CSR_CAP) ? rin[i] : grec[s0 + i];
        int d = (r >> 16) & 255;
        int p = off_l[d] + atomicAdd(&fill_l[d], 1);
        u16 sv = (u16)(r & 0xffffu);
        if (p < CSR_CAP) sorted[p] = sv;
        else csr[s0 + p] = sv;
    }
    __syncthreads();
    int m = min(n, CSR_CAP);
    for (int i = t; i < m; i += 256) csr[s0 + i] = sorted[i];
}

// ---------- MFMA GEMM: hp[r] = bf16( (X[r] @ W) * dinv[r] ) ----------
// block = 64 rows x 128 cols, 4 waves (one 16-row band each)

__global__ __launch_bounds__(256, 2) void k_gemm_mfma(const float* __restrict__ X,
                                                      const u16* __restrict__ pw,
                                                      const float* __restrict__ dinv,
                                                      u16* __restrict__ hp, int nrows) {
    __shared__ u16 xp[8192];    // 16 KB: A-frags [ks][wv][lane][8], reused for epilogue
    const int t = threadIdx.x, lane = t & 63, wv = t >> 6;
    const int r0 = blockIdx.x * 64;
    const float4* X4 = (const float4*)X;

    // stage X-tile as fp16 A-frags
#pragma unroll
    for (int it = 0; it < 8; ++it) {
        int idx = it * 256 + t;          // 64 rows x 32 float4-cols
        int rloc = idx >> 5, kq = idx & 31;
        int rr = r0 + rloc;
        float4 xv = (rr < nrows) ? X4[(size_t)rr * 32 + kq]
                                 : make_float4(0.f, 0.f, 0.f, 0.f);
        int ks = kq >> 3, g = (kq >> 1) & 3, half = kq & 1;
        int wvd = rloc >> 4, ln = (rloc & 15) + 16 * g;
        ushort4 p;
        p.x = f2h(xv.x); p.y = f2h(xv.y); p.z = f2h(xv.z); p.w = f2h(xv.w);
        *(ushort4*)&xp[(((ks * 4 + wvd) * 64 + ln) << 3) + half * 4] = p;
    }
    __syncthreads();

    f32x4 acc[8];
#pragma unroll
    for (int c = 0; c < 8; ++c) acc[c] = (f32x4){0.f, 0.f, 0.f, 0.f};

#pragma unroll
    for (int ks = 0; ks < 4; ++ks) {
        f16x8 a = *reinterpret_cast<f16x8*>(&xp[((ks * 4 + wv) * 64 + lane) << 3]);
#pragma unroll
        for (int ct = 0; ct < 8; ++ct) {
            f16x8 b = *reinterpret_cast<const f16x8*>(pw + ((size_t)((ks * 8 + ct) * 64 + lane) << 3));
            acc[ct] = __builtin_amdgcn_mfma_f32_16x16x32_f16(a, b, acc[ct], 0, 0, 0);
        }
    }

    // epilogue: *dinv, ->bf16, swizzled LDS transpose, coalesced store
    float dv[4];
#pragma unroll
    for (int r = 0; r < 4; ++r) {
        int m = r0 + wv * 16 + 4 * (lane >> 4) + r;
        dv[r] = (m < nrows) ? dinv[m] : 0.f;
    }
    __syncthreads();   // xp free
#pragma unroll
    for (int ct = 0; ct < 8; ++ct)
#pragma unroll
        for (int r = 0; r < 4; ++r) {
            int row_local = wv * 16 + 4 * (lane >> 4) + r;
            int colb = ct * 32 + (lane & 15) * 2;
            int byte = row_local * 256 + (colb ^ swz(row_local));
            xp[byte >> 1] = f2bf(acc[ct][r] * dv[r]);
        }
    __syncthreads();
#pragma unroll
    for (int p = 0; p < 4; ++p) {
        int row_local = t >> 2;
        int chunk = (t & 3) + 4 * p;
        int byte = row_local * 256 + ((chunk * 16) ^ swz(row_local));
        uint4 val = *reinterpret_cast<uint4*>(&xp[byte >> 1]);
        int rr = r0 + row_local;
        if (rr < nrows) ((uint4*)hp)[(size_t)rr * 16 + chunk] = val;
    }
}

// ---------- aggregation: out[v] = relu(dinv[v]*(hp[v] + sum_{s->v} hp[s]) + b) ----------

__global__ void k_agg(const uint32* __restrict__ hp, const int* __restrict__ row_start,
                      const u16* __restrict__ csr, const float* __restrict__ dinv,
                      const float* __restrict__ bias, float* __restrict__ out) {
    int wid = threadIdx.x >> 6, lane = threadIdx.x & 63;
    int v = blockIdx.x * 4 + wid;
    if (v >= NN) return;
    float2 acc = make_float2(0.f, 0.f);
    acc_bf2(acc, hp[(size_t)v * 64 + lane]);   // self loop
    int beg = row_start[v], end = row_start[v + 1];
    int e = beg;
    for (; e + 4 <= end; e += 4) {
        int s0 = csr[e], s1 = csr[e + 1], s2 = csr[e + 2], s3 = csr[e + 3];
        uint32 m0 = hp[(size_t)s0 * 64 + lane];
        uint32 m1 = hp[(size_t)s1 * 64 + lane];
        uint32 m2 = hp[(size_t)s2 * 64 + lane];
        uint32 m3 = hp[(size_t)s3 * 64 + lane];
        acc_bf2(acc, m0); acc_bf2(acc, m1); acc_bf2(acc, m2); acc_bf2(acc, m3);
    }
    for (; e < end; ++e) {
        acc_bf2(acc, hp[(size_t)csr[e] * 64 + lane]);
    }
    float dvv = dinv[v];
    float2 bb = ((const float2*)bias)[lane];
    float2 o;
    o.x = fmaxf(acc.x * dvv + bb.x, 0.f);
    o.y = fmaxf(acc.y * dvv + bb.y, 0.f);
    ((float2*)out)[(size_t)v * 64 + lane] = o;
}

// ---------- pooling stage 1 ----------

__global__ __launch_bounds__(256) void k_pool1(const float* __restrict__ h,
                                               const int* __restrict__ batch,
                                               float* __restrict__ pooled) {
    __shared__ int bl[POOL_ROWS];
    const int row0 = blockIdx.x * POOL_ROWS;
    const int rend = min(row0 + POOL_ROWS, NN);
    const int nrows = rend - row0;
    for (int i = threadIdx.x; i < nrows; i += 256) bl[i] = batch[row0 + i];
    __syncthreads();
    const int col2 = threadIdx.x & 63;
    const int rp   = threadIdx.x >> 6;
    const float2* h2 = (const float2*)h;
    float2 acc = make_float2(0.f, 0.f);
    int curg = -1;
    for (int i = rp; i < nrows; i += 4) {
        int g = bl[i];
        if (g != curg) {
            if (curg >= 0) {
                atomicAdd(&pooled[curg * 128 + 2 * col2], acc.x);
                atomicAdd(&pooled[curg * 128 + 2 * col2 + 1], acc.y);
            }
            acc = make_float2(0.f, 0.f);
            curg = g;
        }
        float2 m = h2[(size_t)(row0 + i) * 64 + col2];
        acc.x += m.x; acc.y += m.y;
    }
    if (curg >= 0) {
        atomicAdd(&pooled[curg * 128 + 2 * col2], acc.x);
        atomicAdd(&pooled[curg * 128 + 2 * col2 + 1], acc.y);
    }
}

// ---------- pooling stage 2: mean + linear head ----------

__global__ __launch_bounds__(256) void k_head(const float* __restrict__ pooled,
                                              const int* __restrict__ batch,
                                              const float* __restrict__ Wl,
                                              const float* __restrict__ bl_,
                                              float* __restrict__ out) {
    int g = blockIdx.x, t = threadIdx.x;
    __shared__ int se[2];
    __shared__ float pm[128];
    __shared__ float part[256];
    if (t < 2) {
        int target = g + t;
        int lo = 0, hi = NN;
        while (lo < hi) {
            int mid = (lo + hi) >> 1;
            if (batch[mid] < target) lo = mid + 1; else hi = mid;
        }
        se[t] = lo;
    }
    __syncthreads();
    int cntg = se[1] - se[0];
    float inv = 1.f / (float)(cntg > 0 ? cntg : 1);
    if (t < 128) pm[t] = pooled[g * 128 + t] * inv;
    __syncthreads();
    int col = t & 63, kh = t >> 6;
    float o = 0.f;
    for (int k = kh * 32; k < kh * 32 + 32; ++k) o += pm[k] * Wl[k * OD + col];
    part[t] = o; __syncthreads();
    if (t < OD)
        out[g * OD + t] = part[t] + part[t + 64] + part[t + 128] + part[t + 192] + bl_[t];
}

// ---------- launcher ----------

extern "C" void kernel_launch(void* const* d_in, const int* in_sizes, int n_in,
                              void* d_out, int out_size, void* d_ws, size_t ws_size,
                              hipStream_t stream) {
    const float* x   = (const float*)d_in[0];
    const int*   ei  = (const int*)d_in[1];
    const int*   bat = (const int*)d_in[2];
    const float* W1  = (const float*)d_in[3];
    const float* b1  = (const float*)d_in[4];
    const float* W2  = (const float*)d_in[5];
    const float* b2  = (const float*)d_in[6];
    const float* Wl  = (const float*)d_in[7];
    const float* bl  = (const float*)d_in[8];
    float* out = (float*)d_out;
    const int* src = ei;
    const int* dst = ei + NE;

    char* w = (char*)d_ws;
    size_t off = 0;
    auto alloc = [&](size_t bytes) -> char* {
        char* p = w + off;
        off = (off + bytes + 255) & ~(size_t)255;
        return p;
    };
    float* dinv        = (float*)alloc(NN * 4);
    int*   row_start   = (int*)alloc((NN + 1) * 4);
    int*   bucket_cnt  = (int*)alloc(NBUCK * 4);
    int*   bucket_base = (int*)alloc((NBUCK + 1) * 4);
    int*   bucket_fill = (int*)alloc(NBUCK * 4);
    float* pooled      = (float*)alloc(NG * HD * 4);
    u16*   pw1         = (u16*)alloc(2048 * 16);   // packed W1 fp16 frags
    u16*   pw2         = (u16*)alloc(2048 * 16);   // packed W2 fp16 frags
    uint32* grec       = (uint32*)alloc((size_t)NE * 4);
    u16*   csr         = (u16*)alloc((size_t)NE * 2);
    u16*   hp          = (u16*)alloc((size_t)NN * HD * 2);   // bf16 h'
    float* bufB        = (float*)alloc((size_t)NN * HD * 4); // fp32 layer output

    // no hipMemsetAsync in the graph: packW zeroes bucket_cnt, bscan zeroes pooled

    k_packW<<<8, 256, 0, stream>>>(W1, pw1, bucket_cnt);
    k_packW<<<8, 256, 0, stream>>>(W2, pw2, bucket_cnt);

    k_hist<<<SBLOCKS, 256, 0, stream>>>(dst, bucket_cnt);
    k_bscan<<<1, 256, 0, stream>>>(bucket_cnt, bucket_base, bucket_fill, row_start, pooled);
    k_scatter<<<SBLOCKS, 256, 0, stream>>>(src, dst, bucket_fill, grec);
    k_csr<<<NBUCK, 256, 0, stream>>>(grec, bucket_base, row_start, dinv, csr);

    // conv1
    k_gemm_mfma<<<GEMM_BLOCKS, 256, 0, stream>>>(x, pw1, dinv, hp, NN);
    k_agg<<<(NN + 3) / 4, 256, 0, stream>>>((const uint32*)hp, row_start, csr, dinv, b1, bufB);
    // conv2
    k_gemm_mfma<<<GEMM_BLOCKS, 256, 0, stream>>>(bufB, pw2, dinv, hp, NN);
    k_agg<<<(NN + 3) / 4, 256, 0, stream>>>((const uint32*)hp, row_start, csr, dinv, b2, bufB);
    // pool
    k_pool1<<<(NN + POOL_ROWS - 1) / POOL_ROWS, 256, 0, stream>>>(bufB, bat, pooled);
    k_head<<<NG, 256, 0, stream>>>(pooled, bat, Wl, bl, out);
}

// Round 8
// 161.436 us; speedup vs baseline: 9.6798x; 1.0945x over previous
//
#include <hip/hip_runtime.h>
#include <hip/hip_bf16.h>
#include <cstdint>

#define NN 50000
#define NE 800000
#define HD 128
#define OD 64
#define NG 64
#define NBUCK 196          // buckets of 256 dst nodes
#define SCHUNK 4096        // edges per scatter block
#define SBLOCKS 196        // ceil(800000/4096)
#define CSR_CAP 5120       // per-bucket capacity (mean 4082, +16 sigma)
#define GEMM_BLOCKS 782    // ceil(50000/64)

typedef unsigned int uint32;
typedef unsigned short u16;
typedef _Float16 f16;
typedef _Float16 f16x8 __attribute__((ext_vector_type(8)));
typedef float f32x4 __attribute__((ext_vector_type(4)));

static __device__ __forceinline__ u16 f2h(float f) {
    f16 h = (f16)f;                       // v_cvt_f16_f32, RTNE
    return __builtin_bit_cast(u16, h);
}
static __device__ __forceinline__ float h2f(u16 u) {
    return (float)__builtin_bit_cast(f16, u);
}
static __device__ __forceinline__ void acc_h2(float2& a, uint32 u) {
    a.x += h2f((u16)(u & 0xffffu));
    a.y += h2f((u16)(u >> 16));
}
static __device__ __forceinline__ uint32 pkh2(float x, float y) {
    return (uint32)f2h(x) | ((uint32)f2h(y) << 16);
}
// epilogue LDS transpose swizzle (involution, 16B-granular)
static __device__ __forceinline__ int swz(int row) {
    return ((row & 7) << 4) | ((row & 8) << 3);
}

// ---------- prep: pack W1,W2 to fp16 frag order; zero bucket_fill + pooled ----------
// sigma: k = ks*32 + (lane>>4)*8 + j ; n = ct*16 + (lane&15); A,B share sigma.

__global__ __launch_bounds__(256) void k_prep(const float* __restrict__ W1,
                                              const float* __restrict__ W2,
                                              u16* __restrict__ pw1,
                                              u16* __restrict__ pw2,
                                              int* __restrict__ bucket_fill,
                                              float* __restrict__ pooled) {
    int b = blockIdx.x, t = threadIdx.x;
    if (b == 16) {
        if (t < NBUCK) bucket_fill[t] = 0;
        float4 z = make_float4(0.f, 0.f, 0.f, 0.f);
#pragma unroll
        for (int i = 0; i < 8; ++i) ((float4*)pooled)[i * 256 + t] = z;
        return;
    }
    const float* W = (b < 8) ? W1 : W2;
    u16* pw = (b < 8) ? pw1 : pw2;
    int tau = (b & 7) * 256 + t;                // 0..2047
    int lane = tau & 63, ct = (tau >> 6) & 7, ks = (tau >> 9) & 3;
    int g = lane >> 4, n = ct * 16 + (lane & 15);
    uint32 pk[4];
#pragma unroll
    for (int jp = 0; jp < 4; ++jp) {
        int k = ks * 32 + g * 8 + jp * 2;
        uint32 lo = f2h(W[k * 128 + n]);
        uint32 hi = f2h(W[(k + 1) * 128 + n]);
        pk[jp] = lo | (hi << 16);
    }
    ((uint4*)pw)[(size_t)((ks * 8 + ct) * 64 + lane)] = make_uint4(pk[0], pk[1], pk[2], pk[3]);
}

// ---------- single-pass bucketed scatter into fixed-capacity strided buckets ----------

__global__ __launch_bounds__(256) void k_scatter(const int* __restrict__ src,
                                                 const int* __restrict__ dst,
                                                 int* __restrict__ bucket_fill,
                                                 uint32* __restrict__ grec) {
    __shared__ uint32 rin[SCHUNK];
    __shared__ uint32 rout[SCHUNK];
    __shared__ int lh[256], ls[256], lf[256], lgb[256];
    int t = threadIdx.x;
    lh[t] = 0; lf[t] = 0;
    __syncthreads();
    int e0 = blockIdx.x * SCHUNK;
    int ne = min(SCHUNK, NE - e0);
    for (int k = 0; k < 16; ++k) {
        int i = k * 256 + t;
        if (i < ne) {
            uint32 rec = ((uint32)dst[e0 + i] << 16) | (uint32)src[e0 + i];
            rin[i] = rec;
            atomicAdd(&lh[rec >> 24], 1);
        }
    }
    __syncthreads();
    int v = lh[t];
    ls[t] = v; __syncthreads();
    for (int off = 1; off < 256; off <<= 1) {
        int u = (t >= off) ? ls[t - off] : 0;
        __syncthreads();
        ls[t] += u;
        __syncthreads();
    }
    int excl = ls[t] - v;
    __syncthreads();
    ls[t] = excl;
    if (t < NBUCK && v > 0) lgb[t] = atomicAdd(&bucket_fill[t], v);
    __syncthreads();
    for (int k = 0; k < 16; ++k) {
        int i = k * 256 + t;
        if (i < ne) {
            uint32 rec = rin[i];
            int b = rec >> 24;
            int p = ls[b] + atomicAdd(&lf[b], 1);
            rout[p] = rec;
        }
    }
    __syncthreads();
    for (int k = 0; k < 16; ++k) {
        int i = k * 256 + t;
        if (i < ne) {
            uint32 rec = rout[i];
            int b = rec >> 24;
            int pos = lgb[b] + (i - ls[b]);
            if (pos < CSR_CAP) grec[(size_t)b * CSR_CAP + pos] = rec;
        }
    }
}

// ---------- per-bucket counting sort -> u16 CSR + packed (rs|deg<<20) + dinv ----------

__global__ __launch_bounds__(256) void k_csr(const uint32* __restrict__ grec,
                                             const int* __restrict__ bucket_fill,
                                             uint32* __restrict__ packed,
                                             float* __restrict__ dinv,
                                             u16* __restrict__ csr) {
    __shared__ uint32 rin[CSR_CAP];
    __shared__ u16 sorted[CSR_CAP];
    __shared__ int cnt_l[256], off_l[256], fill_l[256];
    const int b = blockIdx.x, t = threadIdx.x;
    const int s0 = b * CSR_CAP;
    const int n = min(bucket_fill[b], CSR_CAP);
    cnt_l[t] = 0; fill_l[t] = 0;
    __syncthreads();
    for (int i = t; i < n; i += 256) {
        uint32 r = grec[s0 + i];
        rin[i] = r;
        atomicAdd(&cnt_l[(r >> 16) & 255], 1);
    }
    __syncthreads();
    int v = cnt_l[t];
    off_l[t] = v; __syncthreads();
    for (int off = 1; off < 256; off <<= 1) {
        int u = (t >= off) ? off_l[t - off] : 0;
        __syncthreads();
        off_l[t] += u;
        __syncthreads();
    }
    int excl = off_l[t] - v;
    __syncthreads();
    off_l[t] = excl;
    int vtx = (b << 8) + t;
    if (vtx < NN) {
        packed[vtx] = (uint32)(s0 + excl) | ((uint32)v << 20);
        dinv[vtx] = rsqrtf((float)(v + 1));   // +1 self-loop
    }
    __syncthreads();
    for (int i = t; i < n; i += 256) {
        uint32 r = rin[i];
        int d = (r >> 16) & 255;
        int p = off_l[d] + atomicAdd(&fill_l[d], 1);
        sorted[p] = (u16)(r & 0xffffu);
    }
    __syncthreads();
    for (int i = t; i < n; i += 256) csr[s0 + i] = sorted[i];
}

// ---------- MFMA GEMM (fp32 input): hp = f16((X @ W) * dinv) ----------

__global__ __launch_bounds__(256, 2) void k_gemm_f32(const float* __restrict__ X,
                                                     const u16* __restrict__ pw,
                                                     const float* __restrict__ dinv,
                                                     u16* __restrict__ hp, int nrows) {
    __shared__ u16 xp[8192];    // 16 KB A-frags, reused for epilogue
    const int t = threadIdx.x, lane = t & 63, wv = t >> 6;
    const int r0 = blockIdx.x * 64;
    const float4* X4 = (const float4*)X;
#pragma unroll
    for (int it = 0; it < 8; ++it) {
        int idx = it * 256 + t;          // 64 rows x 32 float4-cols
        int rloc = idx >> 5, kq = idx & 31;
        int rr = r0 + rloc;
        float4 xv = (rr < nrows) ? X4[(size_t)rr * 32 + kq]
                                 : make_float4(0.f, 0.f, 0.f, 0.f);
        int ks = kq >> 3, g = (kq >> 1) & 3, half = kq & 1;
        int wvd = rloc >> 4, ln = (rloc & 15) + 16 * g;
        ushort4 p;
        p.x = f2h(xv.x); p.y = f2h(xv.y); p.z = f2h(xv.z); p.w = f2h(xv.w);
        *(ushort4*)&xp[(((ks * 4 + wvd) * 64 + ln) << 3) + half * 4] = p;
    }
    __syncthreads();
    f32x4 acc[8];
#pragma unroll
    for (int c = 0; c < 8; ++c) acc[c] = (f32x4){0.f, 0.f, 0.f, 0.f};
#pragma unroll
    for (int ks = 0; ks < 4; ++ks) {
        f16x8 a = *reinterpret_cast<f16x8*>(&xp[((ks * 4 + wv) * 64 + lane) << 3]);
#pragma unroll
        for (int ct = 0; ct < 8; ++ct) {
            f16x8 b = *reinterpret_cast<const f16x8*>(pw + ((size_t)((ks * 8 + ct) * 64 + lane) << 3));
            acc[ct] = __builtin_amdgcn_mfma_f32_16x16x32_f16(a, b, acc[ct], 0, 0, 0);
        }
    }
    float dv[4];
#pragma unroll
    for (int r = 0; r < 4; ++r) {
        int m = r0 + wv * 16 + 4 * (lane >> 4) + r;
        dv[r] = (m < nrows) ? dinv[m] : 0.f;
    }
    __syncthreads();
#pragma unroll
    for (int ct = 0; ct < 8; ++ct)
#pragma unroll
        for (int r = 0; r < 4; ++r) {
            int row_local = wv * 16 + 4 * (lane >> 4) + r;
            int colb = ct * 32 + (lane & 15) * 2;
            int byte = row_local * 256 + (colb ^ swz(row_local));
            xp[byte >> 1] = f2h(acc[ct][r] * dv[r]);
        }
    __syncthreads();
#pragma unroll
    for (int p = 0; p < 4; ++p) {
        int row_local = t >> 2;
        int chunk = (t & 3) + 4 * p;
        int byte = row_local * 256 + ((chunk * 16) ^ swz(row_local));
        uint4 val = *reinterpret_cast<uint4*>(&xp[byte >> 1]);
        int rr = r0 + row_local;
        if (rr < nrows) ((uint4*)hp)[(size_t)rr * 16 + chunk] = val;
    }
}

// ---------- MFMA GEMM (f16 input): hp = f16((Xh @ W) * dinv) ----------

__global__ __launch_bounds__(256, 2) void k_gemm_f16(const u16* __restrict__ Xh,
                                                     const u16* __restrict__ pw,
                                                     const float* __restrict__ dinv,
                                                     u16* __restrict__ hp, int nrows) {
    __shared__ u16 xp[8192];
    const int t = threadIdx.x, lane = t & 63, wv = t >> 6;
    const int r0 = blockIdx.x * 64;
    const uint4* X16 = (const uint4*)Xh;
#pragma unroll
    for (int it = 0; it < 4; ++it) {
        int idx = it * 256 + t;          // 64 rows x 16 16B-chunks
        int rloc = idx >> 4, c = idx & 15;
        int rr = r0 + rloc;
        uint4 v = (rr < nrows) ? X16[(size_t)rr * 16 + c]
                               : make_uint4(0u, 0u, 0u, 0u);
        int ks = c >> 2, g = c & 3;
        int wvd = rloc >> 4, ln = (rloc & 15) + 16 * g;
        *(uint4*)&xp[((ks * 4 + wvd) * 64 + ln) << 3] = v;
    }
    __syncthreads();
    f32x4 acc[8];
#pragma unroll
    for (int c = 0; c < 8; ++c) acc[c] = (f32x4){0.f, 0.f, 0.f, 0.f};
#pragma unroll
    for (int ks = 0; ks < 4; ++ks) {
        f16x8 a = *reinterpret_cast<f16x8*>(&xp[((ks * 4 + wv) * 64 + lane) << 3]);
#pragma unroll
        for (int ct = 0; ct < 8; ++ct) {
            f16x8 b = *reinterpret_cast<const f16x8*>(pw + ((size_t)((ks * 8 + ct) * 64 + lane) << 3));
            acc[ct] = __builtin_amdgcn_mfma_f32_16x16x32_f16(a, b, acc[ct], 0, 0, 0);
        }
    }
    float dv[4];
#pragma unroll
    for (int r = 0; r < 4; ++r) {
        int m = r0 + wv * 16 + 4 * (lane >> 4) + r;
        dv[r] = (m < nrows) ? dinv[m] : 0.f;
    }
    __syncthreads();
#pragma unroll
    for (int ct = 0; ct < 8; ++ct)
#pragma unroll
        for (int r = 0; r < 4; ++r) {
            int row_local = wv * 16 + 4 * (lane >> 4) + r;
            int colb = ct * 32 + (lane & 15) * 2;
            int byte = row_local * 256 + (colb ^ swz(row_local));
            xp[byte >> 1] = f2h(acc[ct][r] * dv[r]);
        }
    __syncthreads();
#pragma unroll
    for (int p = 0; p < 4; ++p) {
        int row_local = t >> 2;
        int chunk = (t & 3) + 4 * p;
        int byte = row_local * 256 + ((chunk * 16) ^ swz(row_local));
        uint4 val = *reinterpret_cast<uint4*>(&xp[byte >> 1]);
        int rr = r0 + row_local;
        if (rr < nrows) ((uint4*)hp)[(size_t)rr * 16 + chunk] = val;
    }
}

// ---------- aggregation: outh[v] = f16(relu(dinv[v]*(hp[v] + sum hp[s]) + b)) ----------

__global__ void k_agg(const uint32* __restrict__ hp, const uint32* __restrict__ packed,
                      const u16* __restrict__ csr, const float* __restrict__ dinv,
                      const float* __restrict__ bias, uint32* __restrict__ outh) {
    int wid = threadIdx.x >> 6, lane = threadIdx.x & 63;
    int v = blockIdx.x * 4 + wid;
    if (v >= NN) return;
    float2 acc = make_float2(0.f, 0.f);
    acc_h2(acc, hp[(size_t)v * 64 + lane]);   // self loop
    uint32 pk = packed[v];
    int e = (int)(pk & 0xFFFFFu);
    int end = e + (int)(pk >> 20);
    for (; e + 4 <= end; e += 4) {
        int s0 = csr[e], s1 = csr[e + 1], s2 = csr[e + 2], s3 = csr[e + 3];
        uint32 m0 = hp[(size_t)s0 * 64 + lane];
        uint32 m1 = hp[(size_t)s1 * 64 + lane];
        uint32 m2 = hp[(size_t)s2 * 64 + lane];
        uint32 m3 = hp[(size_t)s3 * 64 + lane];
        acc_h2(acc, m0); acc_h2(acc, m1); acc_h2(acc, m2); acc_h2(acc, m3);
    }
    for (; e < end; ++e) acc_h2(acc, hp[(size_t)csr[e] * 64 + lane]);
    float dvv = dinv[v];
    float2 bb = ((const float2*)bias)[lane];
    float ox = fmaxf(acc.x * dvv + bb.x, 0.f);
    float oy = fmaxf(acc.y * dvv + bb.y, 0.f);
    outh[(size_t)v * 64 + lane] = pkh2(ox, oy);
}

// ---------- pooling stage 1: f16 in, fp32 segment-sum into pooled[64][128] ----------

__global__ __launch_bounds__(256) void k_pool1(const uint32* __restrict__ h,
                                               const int* __restrict__ batch,
                                               float* __restrict__ pooled) {
    __shared__ int bl[256];
    const int row0 = blockIdx.x * 256;
    const int rend = min(row0 + 256, NN);
    const int nrows = rend - row0;
    for (int i = threadIdx.x; i < nrows; i += 256) bl[i] = batch[row0 + i];
    __syncthreads();
    const int col2 = threadIdx.x & 63;
    const int rp   = threadIdx.x >> 6;
    float2 acc = make_float2(0.f, 0.f);
    int curg = -1;
    for (int i = rp; i < nrows; i += 4) {
        int g = bl[i];
        if (g != curg) {
            if (curg >= 0) {
                atomicAdd(&pooled[curg * 128 + 2 * col2], acc.x);
                atomicAdd(&pooled[curg * 128 + 2 * col2 + 1], acc.y);
            }
            acc = make_float2(0.f, 0.f);
            curg = g;
        }
        acc_h2(acc, h[(size_t)(row0 + i) * 64 + col2]);
    }
    if (curg >= 0) {
        atomicAdd(&pooled[curg * 128 + 2 * col2], acc.x);
        atomicAdd(&pooled[curg * 128 + 2 * col2 + 1], acc.y);
    }
}

// ---------- pooling stage 2: mean + linear head ----------

__global__ __launch_bounds__(256) void k_head(const float* __restrict__ pooled,
                                              const int* __restrict__ batch,
                                              const float* __restrict__ Wl,
                                              const float* __restrict__ bl_,
                                              float* __restrict__ out) {
    int g = blockIdx.x, t = threadIdx.x;
    __shared__ int se[2];
    __shared__ float pm[128];
    __shared__ float part[256];
    if (t < 2) {
        int target = g + t;
        int lo = 0, hi = NN;
        while (lo < hi) {
            int mid = (lo + hi) >> 1;
            if (batch[mid] < target) lo = mid + 1; else hi = mid;
        }
        se[t] = lo;
    }
    __syncthreads();
    int cntg = se[1] - se[0];
    float inv = 1.f / (float)(cntg > 0 ? cntg : 1);
    if (t < 128) pm[t] = pooled[g * 128 + t] * inv;
    __syncthreads();
    int col = t & 63, kh = t >> 6;
    float o = 0.f;
    for (int k = kh * 32; k < kh * 32 + 32; ++k) o += pm[k] * Wl[k * OD + col];
    part[t] = o; __syncthreads();
    if (t < OD)
        out[g * OD + t] = part[t] + part[t + 64] + part[t + 128] + part[t + 192] + bl_[t];
}

// ---------- launcher ----------

extern "C" void kernel_launch(void* const* d_in, const int* in_sizes, int n_in,
                              void* d_out, int out_size, void* d_ws, size_t ws_size,
                              hipStream_t stream) {
    const float* x   = (const float*)d_in[0];
    const int*   ei  = (const int*)d_in[1];
    const int*   bat = (const int*)d_in[2];
    const float* W1  = (const float*)d_in[3];
    const float* b1  = (const float*)d_in[4];
    const float* W2  = (const float*)d_in[5];
    const float* b2  = (const float*)d_in[6];
    const float* Wl  = (const float*)d_in[7];
    const float* bl  = (const float*)d_in[8];
    float* out = (float*)d_out;
    const int* src = ei;
    const int* dst = ei + NE;

    char* w = (char*)d_ws;
    size_t off = 0;
    auto alloc = [&](size_t bytes) -> char* {
        char* p = w + off;
        off = (off + bytes + 255) & ~(size_t)255;
        return p;
    };
    float*  dinv        = (float*)alloc(NN * 4);
    uint32* packed      = (uint32*)alloc(NN * 4);
    int*    bucket_fill = (int*)alloc(NBUCK * 4);
    float*  pooled      = (float*)alloc(NG * HD * 4);
    u16*    pw1         = (u16*)alloc(2048 * 16);
    u16*    pw2         = (u16*)alloc(2048 * 16);
    uint32* grec        = (uint32*)alloc((size_t)NBUCK * CSR_CAP * 4);
    u16*    csr         = (u16*)alloc((size_t)NBUCK * CSR_CAP * 2);
    u16*    hp          = (u16*)alloc((size_t)NN * HD * 2);   // f16 h'
    u16*    h2          = (u16*)alloc((size_t)NN * HD * 2);   // f16 layer output

    k_prep<<<17, 256, 0, stream>>>(W1, W2, pw1, pw2, bucket_fill, pooled);
    k_scatter<<<SBLOCKS, 256, 0, stream>>>(src, dst, bucket_fill, grec);
    k_csr<<<NBUCK, 256, 0, stream>>>(grec, bucket_fill, packed, dinv, csr);

    // conv1
    k_gemm_f32<<<GEMM_BLOCKS, 256, 0, stream>>>(x, pw1, dinv, hp, NN);
    k_agg<<<(NN + 3) / 4, 256, 0, stream>>>((const uint32*)hp, packed, csr, dinv, b1, (uint32*)h2);
    // conv2
    k_gemm_f16<<<GEMM_BLOCKS, 256, 0, stream>>>(h2, pw2, dinv, hp, NN);
    k_agg<<<(NN + 3) / 4, 256, 0, stream>>>((const uint32*)hp, packed, csr, dinv, b2, (uint32*)h2);
    // pool + head
    k_pool1<<<(NN + 255) / 256, 256, 0, stream>>>((const uint32*)h2, bat, pooled);
    k_head<<<NG, 256, 0, stream>>>(pooled, bat, Wl, bl, out);
}

// Round 9
// 152.116 us; speedup vs baseline: 10.2729x; 1.0613x over previous
//
#include <hip/hip_runtime.h>
#include <hip/hip_bf16.h>
#include <cstdint>

#define NN 50000
#define NE 800000
#define HD 128
#define OD 64
#define NG 64
#define NBUCK 196          // buckets of 256 dst nodes
#define SCHUNK 4096        // edges per scatter block
#define SBLOCKS 196        // ceil(800000/4096)
#define CSR_CAP 5120       // per-bucket capacity (mean 4082, +16 sigma)
#define GEMM_BLOCKS 782    // ceil(50000/64)

typedef unsigned int uint32;
typedef unsigned short u16;
typedef _Float16 f16;
typedef _Float16 f16x8 __attribute__((ext_vector_type(8)));
typedef float f32x4 __attribute__((ext_vector_type(4)));

static __device__ __forceinline__ u16 f2h(float f) {
    f16 h = (f16)f;                       // v_cvt_f16_f32, RTNE
    return __builtin_bit_cast(u16, h);
}
static __device__ __forceinline__ float h2f(u16 u) {
    return (float)__builtin_bit_cast(f16, u);
}
static __device__ __forceinline__ void acc_h2(float2& a, uint32 u) {
    a.x += h2f((u16)(u & 0xffffu));
    a.y += h2f((u16)(u >> 16));
}
static __device__ __forceinline__ uint32 pkh2(float x, float y) {
    return (uint32)f2h(x) | ((uint32)f2h(y) << 16);
}
// epilogue LDS transpose swizzle (involution, 16B-granular)
static __device__ __forceinline__ int swz(int row) {
    return ((row & 7) << 4) | ((row & 8) << 3);
}

// ---------- prep: pack W1,W2 to fp16 frag order; zero bucket_fill + pooled ----------
// sigma: k = ks*32 + (lane>>4)*8 + j ; n = ct*16 + (lane&15); A,B share sigma.

__global__ __launch_bounds__(256) void k_prep(const float* __restrict__ W1,
                                              const float* __restrict__ W2,
                                              u16* __restrict__ pw1,
                                              u16* __restrict__ pw2,
                                              int* __restrict__ bucket_fill,
                                              float* __restrict__ pooled) {
    int b = blockIdx.x, t = threadIdx.x;
    if (b == 16) {
        if (t < NBUCK) bucket_fill[t] = 0;
        float4 z = make_float4(0.f, 0.f, 0.f, 0.f);
#pragma unroll
        for (int i = 0; i < 8; ++i) ((float4*)pooled)[i * 256 + t] = z;
        return;
    }
    const float* W = (b < 8) ? W1 : W2;
    u16* pw = (b < 8) ? pw1 : pw2;
    int tau = (b & 7) * 256 + t;                // 0..2047
    int lane = tau & 63, ct = (tau >> 6) & 7, ks = (tau >> 9) & 3;
    int g = lane >> 4, n = ct * 16 + (lane & 15);
    uint32 pk[4];
#pragma unroll
    for (int jp = 0; jp < 4; ++jp) {
        int k = ks * 32 + g * 8 + jp * 2;
        uint32 lo = f2h(W[k * 128 + n]);
        uint32 hi = f2h(W[(k + 1) * 128 + n]);
        pk[jp] = lo | (hi << 16);
    }
    ((uint4*)pw)[(size_t)((ks * 8 + ct) * 64 + lane)] = make_uint4(pk[0], pk[1], pk[2], pk[3]);
}

// ---------- single-pass bucketed scatter into fixed-capacity strided buckets ----------

__global__ __launch_bounds__(256) void k_scatter(const int* __restrict__ src,
                                                 const int* __restrict__ dst,
                                                 int* __restrict__ bucket_fill,
                                                 uint32* __restrict__ grec) {
    __shared__ uint32 rin[SCHUNK];
    __shared__ uint32 rout[SCHUNK];
    __shared__ int lh[256], ls[256], lf[256], lgb[256];
    int t = threadIdx.x;
    lh[t] = 0; lf[t] = 0;
    __syncthreads();
    int e0 = blockIdx.x * SCHUNK;
    int ne = min(SCHUNK, NE - e0);
    for (int k = 0; k < 16; ++k) {
        int i = k * 256 + t;
        if (i < ne) {
            uint32 rec = ((uint32)dst[e0 + i] << 16) | (uint32)src[e0 + i];
            rin[i] = rec;
            atomicAdd(&lh[rec >> 24], 1);
        }
    }
    __syncthreads();
    int v = lh[t];
    ls[t] = v; __syncthreads();
    for (int off = 1; off < 256; off <<= 1) {
        int u = (t >= off) ? ls[t - off] : 0;
        __syncthreads();
        ls[t] += u;
        __syncthreads();
    }
    int excl = ls[t] - v;
    __syncthreads();
    ls[t] = excl;
    if (t < NBUCK && v > 0) lgb[t] = atomicAdd(&bucket_fill[t], v);
    __syncthreads();
    for (int k = 0; k < 16; ++k) {
        int i = k * 256 + t;
        if (i < ne) {
            uint32 rec = rin[i];
            int b = rec >> 24;
            int p = ls[b] + atomicAdd(&lf[b], 1);
            rout[p] = rec;
        }
    }
    __syncthreads();
    for (int k = 0; k < 16; ++k) {
        int i = k * 256 + t;
        if (i < ne) {
            uint32 rec = rout[i];
            int b = rec >> 24;
            int pos = lgb[b] + (i - ls[b]);
            if (pos < CSR_CAP) grec[(size_t)b * CSR_CAP + pos] = rec;
        }
    }
}

// ---------- per-bucket counting sort -> u16 CSR + packed (rs|deg<<20) + dinv ----------

__global__ __launch_bounds__(256) void k_csr(const uint32* __restrict__ grec,
                                             const int* __restrict__ bucket_fill,
                                             uint32* __restrict__ packed,
                                             float* __restrict__ dinv,
                                             u16* __restrict__ csr) {
    __shared__ uint32 rin[CSR_CAP];
    __shared__ u16 sorted[CSR_CAP];
    __shared__ int cnt_l[256], off_l[256], fill_l[256];
    const int b = blockIdx.x, t = threadIdx.x;
    const int s0 = b * CSR_CAP;
    const int n = min(bucket_fill[b], CSR_CAP);
    cnt_l[t] = 0; fill_l[t] = 0;
    __syncthreads();
    for (int i = t; i < n; i += 256) {
        uint32 r = grec[s0 + i];
        rin[i] = r;
        atomicAdd(&cnt_l[(r >> 16) & 255], 1);
    }
    __syncthreads();
    int v = cnt_l[t];
    off_l[t] = v; __syncthreads();
    for (int off = 1; off < 256; off <<= 1) {
        int u = (t >= off) ? off_l[t - off] : 0;
        __syncthreads();
        off_l[t] += u;
        __syncthreads();
    }
    int excl = off_l[t] - v;
    __syncthreads();
    off_l[t] = excl;
    int vtx = (b << 8) + t;
    if (vtx < NN) {
        packed[vtx] = (uint32)(s0 + excl) | ((uint32)v << 20);
        dinv[vtx] = rsqrtf((float)(v + 1));   // +1 self-loop
    }
    __syncthreads();
    for (int i = t; i < n; i += 256) {
        uint32 r = rin[i];
        int d = (r >> 16) & 255;
        int p = off_l[d] + atomicAdd(&fill_l[d], 1);
        sorted[p] = (u16)(r & 0xffffu);
    }
    __syncthreads();
    for (int i = t; i < n; i += 256) csr[s0 + i] = sorted[i];
}

// ---------- MFMA GEMM (fp32 input): hp = f16((X @ W) * dinv) ----------

__global__ __launch_bounds__(256, 2) void k_gemm_f32(const float* __restrict__ X,
                                                     const u16* __restrict__ pw,
                                                     const float* __restrict__ dinv,
                                                     u16* __restrict__ hp, int nrows) {
    __shared__ u16 xp[8192];    // 16 KB A-frags, reused for epilogue
    const int t = threadIdx.x, lane = t & 63, wv = t >> 6;
    const int r0 = blockIdx.x * 64;
    const float4* X4 = (const float4*)X;
#pragma unroll
    for (int it = 0; it < 8; ++it) {
        int idx = it * 256 + t;          // 64 rows x 32 float4-cols
        int rloc = idx >> 5, kq = idx & 31;
        int rr = r0 + rloc;
        float4 xv = (rr < nrows) ? X4[(size_t)rr * 32 + kq]
                                 : make_float4(0.f, 0.f, 0.f, 0.f);
        int ks = kq >> 3, g = (kq >> 1) & 3, half = kq & 1;
        int wvd = rloc >> 4, ln = (rloc & 15) + 16 * g;
        ushort4 p;
        p.x = f2h(xv.x); p.y = f2h(xv.y); p.z = f2h(xv.z); p.w = f2h(xv.w);
        *(ushort4*)&xp[(((ks * 4 + wvd) * 64 + ln) << 3) + half * 4] = p;
    }
    __syncthreads();
    f32x4 acc[8];
#pragma unroll
    for (int c = 0; c < 8; ++c) acc[c] = (f32x4){0.f, 0.f, 0.f, 0.f};
#pragma unroll
    for (int ks = 0; ks < 4; ++ks) {
        f16x8 a = *reinterpret_cast<f16x8*>(&xp[((ks * 4 + wv) * 64 + lane) << 3]);
#pragma unroll
        for (int ct = 0; ct < 8; ++ct) {
            f16x8 b = *reinterpret_cast<const f16x8*>(pw + ((size_t)((ks * 8 + ct) * 64 + lane) << 3));
            acc[ct] = __builtin_amdgcn_mfma_f32_16x16x32_f16(a, b, acc[ct], 0, 0, 0);
        }
    }
    float dv[4];
#pragma unroll
    for (int r = 0; r < 4; ++r) {
        int m = r0 + wv * 16 + 4 * (lane >> 4) + r;
        dv[r] = (m < nrows) ? dinv[m] : 0.f;
    }
    __syncthreads();
#pragma unroll
    for (int ct = 0; ct < 8; ++ct)
#pragma unroll
        for (int r = 0; r < 4; ++r) {
            int row_local = wv * 16 + 4 * (lane >> 4) + r;
            int colb = ct * 32 + (lane & 15) * 2;
            int byte = row_local * 256 + (colb ^ swz(row_local));
            xp[byte >> 1] = f2h(acc[ct][r] * dv[r]);
        }
    __syncthreads();
#pragma unroll
    for (int p = 0; p < 4; ++p) {
        int row_local = t >> 2;
        int chunk = (t & 3) + 4 * p;
        int byte = row_local * 256 + ((chunk * 16) ^ swz(row_local));
        uint4 val = *reinterpret_cast<uint4*>(&xp[byte >> 1]);
        int rr = r0 + row_local;
        if (rr < nrows) ((uint4*)hp)[(size_t)rr * 16 + chunk] = val;
    }
}

// ---------- MFMA GEMM (f16 input): hp = f16((Xh @ W) * dinv) ----------

__global__ __launch_bounds__(256, 2) void k_gemm_f16(const u16* __restrict__ Xh,
                                                     const u16* __restrict__ pw,
                                                     const float* __restrict__ dinv,
                                                     u16* __restrict__ hp, int nrows) {
    __shared__ u16 xp[8192];
    const int t = threadIdx.x, lane = t & 63, wv = t >> 6;
    const int r0 = blockIdx.x * 64;
    const uint4* X16 = (const uint4*)Xh;
#pragma unroll
    for (int it = 0; it < 4; ++it) {
        int idx = it * 256 + t;          // 64 rows x 16 16B-chunks
        int rloc = idx >> 4, c = idx & 15;
        int rr = r0 + rloc;
        uint4 v = (rr < nrows) ? X16[(size_t)rr * 16 + c]
                               : make_uint4(0u, 0u, 0u, 0u);
        int ks = c >> 2, g = c & 3;
        int wvd = rloc >> 4, ln = (rloc & 15) + 16 * g;
        *(uint4*)&xp[((ks * 4 + wvd) * 64 + ln) << 3] = v;
    }
    __syncthreads();
    f32x4 acc[8];
#pragma unroll
    for (int c = 0; c < 8; ++c) acc[c] = (f32x4){0.f, 0.f, 0.f, 0.f};
#pragma unroll
    for (int ks = 0; ks < 4; ++ks) {
        f16x8 a = *reinterpret_cast<f16x8*>(&xp[((ks * 4 + wv) * 64 + lane) << 3]);
#pragma unroll
        for (int ct = 0; ct < 8; ++ct) {
            f16x8 b = *reinterpret_cast<const f16x8*>(pw + ((size_t)((ks * 8 + ct) * 64 + lane) << 3));
            acc[ct] = __builtin_amdgcn_mfma_f32_16x16x32_f16(a, b, acc[ct], 0, 0, 0);
        }
    }
    float dv[4];
#pragma unroll
    for (int r = 0; r < 4; ++r) {
        int m = r0 + wv * 16 + 4 * (lane >> 4) + r;
        dv[r] = (m < nrows) ? dinv[m] : 0.f;
    }
    __syncthreads();
#pragma unroll
    for (int ct = 0; ct < 8; ++ct)
#pragma unroll
        for (int r = 0; r < 4; ++r) {
            int row_local = wv * 16 + 4 * (lane >> 4) + r;
            int colb = ct * 32 + (lane & 15) * 2;
            int byte = row_local * 256 + (colb ^ swz(row_local));
            xp[byte >> 1] = f2h(acc[ct][r] * dv[r]);
        }
    __syncthreads();
#pragma unroll
    for (int p = 0; p < 4; ++p) {
        int row_local = t >> 2;
        int chunk = (t & 3) + 4 * p;
        int byte = row_local * 256 + ((chunk * 16) ^ swz(row_local));
        uint4 val = *reinterpret_cast<uint4*>(&xp[byte >> 1]);
        int rr = r0 + row_local;
        if (rr < nrows) ((uint4*)hp)[(size_t)rr * 16 + chunk] = val;
    }
}

// ---------- aggregation (wide): wave = 1 node, 16 lanes/edge, uint4 loads ----------
// lane: slot = lane>>4 (edge slot 0..3), colg = lane&15 (16B column group)
// outh[v] = f16(relu(dinv[v]*(hp[v] + sum hp[s]) + b))

__global__ __launch_bounds__(256) void k_agg(const uint32* __restrict__ hp,
                                             const uint32* __restrict__ packed,
                                             const u16* __restrict__ csr,
                                             const float* __restrict__ dinv,
                                             const float* __restrict__ bias,
                                             uint32* __restrict__ outh) {
    const int lane = threadIdx.x & 63;
    const int v = blockIdx.x * 4 + (threadIdx.x >> 6);
    if (v >= NN) return;
    const int slot = lane >> 4, colg = lane & 15;
    const uint4* hp16 = (const uint4*)hp;

    float acc[8];
#pragma unroll
    for (int j = 0; j < 8; ++j) acc[j] = 0.f;

    // self-loop: counted once (slot 0 only, pre-reduction)
    if (slot == 0) {
        uint4 m = hp16[(size_t)v * 16 + colg];
        acc[0] += h2f((u16)(m.x & 0xffffu)); acc[1] += h2f((u16)(m.x >> 16));
        acc[2] += h2f((u16)(m.y & 0xffffu)); acc[3] += h2f((u16)(m.y >> 16));
        acc[4] += h2f((u16)(m.z & 0xffffu)); acc[5] += h2f((u16)(m.z >> 16));
        acc[6] += h2f((u16)(m.w & 0xffffu)); acc[7] += h2f((u16)(m.w >> 16));
    }

    uint32 pk = packed[v];
    const int e0 = (int)(pk & 0xFFFFFu);
    const int end = e0 + (int)(pk >> 20);
    int idx = e0 + slot;

    // 4-deep unroll: 16 edges in flight per wave (4 x uint4 per lane)
    for (; idx + 12 < end; idx += 16) {
        int s0 = csr[idx], s1 = csr[idx + 4], s2 = csr[idx + 8], s3 = csr[idx + 12];
        uint4 m0 = hp16[(size_t)s0 * 16 + colg];
        uint4 m1 = hp16[(size_t)s1 * 16 + colg];
        uint4 m2 = hp16[(size_t)s2 * 16 + colg];
        uint4 m3 = hp16[(size_t)s3 * 16 + colg];
#pragma unroll
        for (int q = 0; q < 4; ++q) {
            uint4 m = (q == 0) ? m0 : (q == 1) ? m1 : (q == 2) ? m2 : m3;
            acc[0] += h2f((u16)(m.x & 0xffffu)); acc[1] += h2f((u16)(m.x >> 16));
            acc[2] += h2f((u16)(m.y & 0xffffu)); acc[3] += h2f((u16)(m.y >> 16));
            acc[4] += h2f((u16)(m.z & 0xffffu)); acc[5] += h2f((u16)(m.z >> 16));
            acc[6] += h2f((u16)(m.w & 0xffffu)); acc[7] += h2f((u16)(m.w >> 16));
        }
    }
    for (; idx < end; idx += 4) {
        int s = csr[idx];
        uint4 m = hp16[(size_t)s * 16 + colg];
        acc[0] += h2f((u16)(m.x & 0xffffu)); acc[1] += h2f((u16)(m.x >> 16));
        acc[2] += h2f((u16)(m.y & 0xffffu)); acc[3] += h2f((u16)(m.y >> 16));
        acc[4] += h2f((u16)(m.z & 0xffffu)); acc[5] += h2f((u16)(m.z >> 16));
        acc[6] += h2f((u16)(m.w & 0xffffu)); acc[7] += h2f((u16)(m.w >> 16));
    }

    // reduce across the 4 edge slots (lanes differ only in bit4,bit5)
#pragma unroll
    for (int j = 0; j < 8; ++j) {
        acc[j] += __shfl_xor(acc[j], 16, 64);
        acc[j] += __shfl_xor(acc[j], 32, 64);
    }

    if (slot == 0) {
        float dvv = dinv[v];
        float4 ba = ((const float4*)bias)[colg * 2];
        float4 bb = ((const float4*)bias)[colg * 2 + 1];
        uint4 o;
        o.x = pkh2(fmaxf(acc[0] * dvv + ba.x, 0.f), fmaxf(acc[1] * dvv + ba.y, 0.f));
        o.y = pkh2(fmaxf(acc[2] * dvv + ba.z, 0.f), fmaxf(acc[3] * dvv + ba.w, 0.f));
        o.z = pkh2(fmaxf(acc[4] * dvv + bb.x, 0.f), fmaxf(acc[5] * dvv + bb.y, 0.f));
        o.w = pkh2(fmaxf(acc[6] * dvv + bb.z, 0.f), fmaxf(acc[7] * dvv + bb.w, 0.f));
        ((uint4*)outh)[(size_t)v * 16 + colg] = o;
    }
}

// ---------- pooling stage 1: f16 in, fp32 segment-sum into pooled[64][128] ----------

__global__ __launch_bounds__(256) void k_pool1(const uint32* __restrict__ h,
                                               const int* __restrict__ batch,
                                               float* __restrict__ pooled) {
    __shared__ int bl[256];
    const int row0 = blockIdx.x * 256;
    const int rend = min(row0 + 256, NN);
    const int nrows = rend - row0;
    for (int i = threadIdx.x; i < nrows; i += 256) bl[i] = batch[row0 + i];
    __syncthreads();
    const int col2 = threadIdx.x & 63;
    const int rp   = threadIdx.x >> 6;
    float2 acc = make_float2(0.f, 0.f);
    int curg = -1;
    for (int i = rp; i < nrows; i += 4) {
        int g = bl[i];
        if (g != curg) {
            if (curg >= 0) {
                atomicAdd(&pooled[curg * 128 + 2 * col2], acc.x);
                atomicAdd(&pooled[curg * 128 + 2 * col2 + 1], acc.y);
            }
            acc = make_float2(0.f, 0.f);
            curg = g;
        }
        acc_h2(acc, h[(size_t)(row0 + i) * 64 + col2]);
    }
    if (curg >= 0) {
        atomicAdd(&pooled[curg * 128 + 2 * col2], acc.x);
        atomicAdd(&pooled[curg * 128 + 2 * col2 + 1], acc.y);
    }
}

// ---------- pooling stage 2: mean + linear head ----------

__global__ __launch_bounds__(256) void k_head(const float* __restrict__ pooled,
                                              const int* __restrict__ batch,
                                              const float* __restrict__ Wl,
                                              const float* __restrict__ bl_,
                                              float* __restrict__ out) {
    int g = blockIdx.x, t = threadIdx.x;
    __shared__ int se[2];
    __shared__ float pm[128];
    __shared__ float part[256];
    if (t < 2) {
        int target = g + t;
        int lo = 0, hi = NN;
        while (lo < hi) {
            int mid = (lo + hi) >> 1;
            if (batch[mid] < target) lo = mid + 1; else hi = mid;
        }
        se[t] = lo;
    }
    __syncthreads();
    int cntg = se[1] - se[0];
    float inv = 1.f / (float)(cntg > 0 ? cntg : 1);
    if (t < 128) pm[t] = pooled[g * 128 + t] * inv;
    __syncthreads();
    int col = t & 63, kh = t >> 6;
    float o = 0.f;
    for (int k = kh * 32; k < kh * 32 + 32; ++k) o += pm[k] * Wl[k * OD + col];
    part[t] = o; __syncthreads();
    if (t < OD)
        out[g * OD + t] = part[t] + part[t + 64] + part[t + 128] + part[t + 192] + bl_[t];
}

// ---------- launcher ----------

extern "C" void kernel_launch(void* const* d_in, const int* in_sizes, int n_in,
                              void* d_out, int out_size, void* d_ws, size_t ws_size,
                              hipStream_t stream) {
    const float* x   = (const float*)d_in[0];
    const int*   ei  = (const int*)d_in[1];
    const int*   bat = (const int*)d_in[2];
    const float* W1  = (const float*)d_in[3];
    const float* b1  = (const float*)d_in[4];
    const float* W2  = (const float*)d_in[5];
    const float* b2  = (const float*)d_in[6];
    const float* Wl  = (const float*)d_in[7];
    const float* bl  = (const float*)d_in[8];
    float* out = (float*)d_out;
    const int* src = ei;
    const int* dst = ei + NE;

    char* w = (char*)d_ws;
    size_t off = 0;
    auto alloc = [&](size_t bytes) -> char* {
        char* p = w + off;
        off = (off + bytes + 255) & ~(size_t)255;
        return p;
    };
    float*  dinv        = (float*)alloc(NN * 4);
    uint32* packed      = (uint32*)alloc(NN * 4);
    int*    bucket_fill = (int*)alloc(NBUCK * 4);
    float*  pooled      = (float*)alloc(NG * HD * 4);
    u16*    pw1         = (u16*)alloc(2048 * 16);
    u16*    pw2         = (u16*)alloc(2048 * 16);
    uint32* grec        = (uint32*)alloc((size_t)NBUCK * CSR_CAP * 4);
    u16*    csr         = (u16*)alloc((size_t)NBUCK * CSR_CAP * 2);
    u16*    hp          = (u16*)alloc((size_t)NN * HD * 2);   // f16 h'
    u16*    h2          = (u16*)alloc((size_t)NN * HD * 2);   // f16 layer output

    k_prep<<<17, 256, 0, stream>>>(W1, W2, pw1, pw2, bucket_fill, pooled);
    k_scatter<<<SBLOCKS, 256, 0, stream>>>(src, dst, bucket_fill, grec);
    k_csr<<<NBUCK, 256, 0, stream>>>(grec, bucket_fill, packed, dinv, csr);

    // conv1
    k_gemm_f32<<<GEMM_BLOCKS, 256, 0, stream>>>(x, pw1, dinv, hp, NN);
    k_agg<<<(NN + 3) / 4, 256, 0, stream>>>((const uint32*)hp, packed, csr, dinv, b1, (uint32*)h2);
    // conv2
    k_gemm_f16<<<GEMM_BLOCKS, 256, 0, stream>>>(h2, pw2, dinv, hp, NN);
    k_agg<<<(NN + 3) / 4, 256, 0, stream>>>((const uint32*)hp, packed, csr, dinv, b2, (uint32*)h2);
    // pool + head
    k_pool1<<<(NN + 255) / 256, 256, 0, stream>>>((const uint32*)h2, bat, pooled);
    k_head<<<NG, 256, 0, stream>>>(pooled, bat, Wl, bl, out);
}